// Round 5
// baseline (630.038 us; speedup 1.0000x reference)
//
#include <hip/hip_runtime.h>

typedef unsigned short ushortT;
typedef __bf16 bf16x8 __attribute__((ext_vector_type(8)));
typedef float f32x4 __attribute__((ext_vector_type(4)));

// Problem constants
#define BB   2
#define LL   2048
#define DM   768
#define HH   12
#define FT   16
#define HD   64
#define DEXP 273      // 1 + 16 + 256
#define CH   128      // chunk length
#define NC   16       // chunks per sequence (LL/CH)
#define NBH  24       // BB*HH
#define NBLK 384      // NBH*NC
#define C2f  0.17677669529663687f   // 1/(4*sqrt(2))
#define KH   768      // K per half
#define KP   1536     // packed row length: [hi(768) | lo(768)]

// ---------------- split helpers ----------------
__device__ __forceinline__ void split_bf16(float x, ushortT& hi, ushortT& lo) {
  unsigned b = __float_as_uint(x);
  unsigned r = b + 0x7FFFu + ((b >> 16) & 1u);  // RNE to bf16
  hi = (ushortT)(r >> 16);
  float hf = __uint_as_float((unsigned)hi << 16);
  lo = (ushortT)(__float_as_uint(x - hf) >> 16);  // truncate
}

// X [M][768] f32 -> Xh [M][1536] bf16 = [hi | lo]
__global__ __launch_bounds__(256) void pack_a(const float* __restrict__ X,
                                              ushortT* __restrict__ Xh,
                                              int total4) {
  int g = blockIdx.x * 256 + threadIdx.x;
  if (g >= total4) return;
  int m = g / 192, k4 = (g % 192) * 4;
  float4 v = *(const float4*)(X + (size_t)m * 768 + k4);
  ushortT h[4], l[4];
  split_bf16(v.x, h[0], l[0]);
  split_bf16(v.y, h[1], l[1]);
  split_bf16(v.z, h[2], l[2]);
  split_bf16(v.w, h[3], l[3]);
  ushortT* p = Xh + (size_t)m * KP + k4;
  *(ushort4*)p = *(ushort4*)h;
  *(ushort4*)(p + KH) = *(ushort4*)l;
}

// W rows (selected from W0/W1/W2) -> Wh [N][1536] bf16 = [hi | lo]
__global__ __launch_bounds__(256) void pack_w(const float* __restrict__ W0,
                                              const float* __restrict__ W1,
                                              const float* __restrict__ W2,
                                              int n1, int n2,
                                              ushortT* __restrict__ Wh,
                                              int total4) {
  int g = blockIdx.x * 256 + threadIdx.x;
  if (g >= total4) return;
  int n = g / 192, k4 = (g % 192) * 4;
  const float* src = (n < n1 ? W0 + (size_t)n * 768
                    : n < n2 ? W1 + (size_t)(n - n1) * 768
                             : W2 + (size_t)(n - n2) * 768);
  float4 v = *(const float4*)(src + k4);
  ushortT h[4], l[4];
  split_bf16(v.x, h[0], l[0]);
  split_bf16(v.y, h[1], l[1]);
  split_bf16(v.z, h[2], l[2]);
  split_bf16(v.w, h[3], l[3]);
  ushortT* p = Wh + (size_t)n * KP + k4;
  *(ushort4*)p = *(ushort4*)h;
  *(ushort4*)(p + KH) = *(ushort4*)l;
}

// async global->LDS, 16B per lane; lds base must be wave-uniform (lane*16 implicit)
typedef const __attribute__((address_space(1))) unsigned gq_t;
typedef __attribute__((address_space(3))) unsigned lq_t;
__device__ __forceinline__ void gload_lds16(const ushortT* g, ushortT* l) {
  __builtin_amdgcn_global_load_lds((gq_t*)g, (lq_t*)l, 16, 0, 0);
}

// ---------------- MFMA GEMM: Y[M][N] = A[M][KP] @ B[N][KP]^T (3-term split-bf16) -------
// 128x64 tile, 4 waves (2 in M x 2 in N), each wave 64x32 via 4x2 mfma_f32_16x16x32_bf16.
// Grid 1-D, XCD-swizzled: blk -> xcd = blk&7 gets M-tiles [xcd*mtp, (xcd+1)*mtp).
__global__ __launch_bounds__(256) void mfma_gemm(const ushortT* __restrict__ A,
                                                 const ushortT* __restrict__ B,
                                                 float* __restrict__ Y, int ldy,
                                                 int ntiles) {
  __shared__ ushortT sAh[128 * 32], sAl[128 * 32], sBh[64 * 32], sBl[64 * 32];
  const int blk = blockIdx.x;
  const int xcd = blk & 7, slot = blk >> 3;
  const int mtp = gridDim.x / (8 * ntiles);
  const int mt = xcd * mtp + slot / ntiles;
  const int nt = slot % ntiles;
  const int bm = mt * 128, bn = nt * 64;
  const int tid = threadIdx.x, wave = tid >> 6, lane = tid & 63;
  const int srow = lane >> 2, schk = (lane & 3) * 8;  // 16 rows x 4 chunks per iter
  const ushortT* gsrc;
  ushortT* lb;
  int iters;
  switch (wave) {
    case 0:  gsrc = A + (size_t)(bm + srow) * KP + schk;      lb = sAh; iters = 8; break;
    case 1:  gsrc = A + (size_t)(bm + srow) * KP + KH + schk; lb = sAl; iters = 8; break;
    case 2:  gsrc = B + (size_t)(bn + srow) * KP + schk;      lb = sBh; iters = 4; break;
    default: gsrc = B + (size_t)(bn + srow) * KP + KH + schk; lb = sBl; iters = 4; break;
  }
  const int wm = (wave & 1) * 64, wn = (wave >> 1) * 32;
  const int fr = lane & 15, quad = lane >> 4;
  f32x4 acc[4][2] = {};
  for (int k0 = 0; k0 < KH; k0 += 32) {
    __syncthreads();  // previous compute done before LDS overwrite
    for (int it = 0; it < iters; it++)
      gload_lds16(gsrc + k0 + (size_t)it * 16 * KP, lb + it * 512);
    __syncthreads();  // drains vmcnt (compiler-inserted before barrier)
    bf16x8 ah[4], al[4], bh2[2], bl2[2];
#pragma unroll
    for (int mi = 0; mi < 4; mi++) {
      ah[mi] = *(const bf16x8*)&sAh[(wm + mi * 16 + fr) * 32 + quad * 8];
      al[mi] = *(const bf16x8*)&sAl[(wm + mi * 16 + fr) * 32 + quad * 8];
    }
#pragma unroll
    for (int ni = 0; ni < 2; ni++) {
      bh2[ni] = *(const bf16x8*)&sBh[(wn + ni * 16 + fr) * 32 + quad * 8];
      bl2[ni] = *(const bf16x8*)&sBl[(wn + ni * 16 + fr) * 32 + quad * 8];
    }
#pragma unroll
    for (int mi = 0; mi < 4; mi++)
#pragma unroll
      for (int ni = 0; ni < 2; ni++) {
        acc[mi][ni] = __builtin_amdgcn_mfma_f32_16x16x32_bf16(ah[mi], bh2[ni], acc[mi][ni], 0, 0, 0);
        acc[mi][ni] = __builtin_amdgcn_mfma_f32_16x16x32_bf16(ah[mi], bl2[ni], acc[mi][ni], 0, 0, 0);
        acc[mi][ni] = __builtin_amdgcn_mfma_f32_16x16x32_bf16(al[mi], bh2[ni], acc[mi][ni], 0, 0, 0);
      }
  }
  const int orow = quad * 4;
#pragma unroll
  for (int mi = 0; mi < 4; mi++)
#pragma unroll
    for (int ni = 0; ni < 2; ni++) {
      float* yp = Y + (size_t)(bm + wm + mi * 16 + orow) * ldy + bn + wn + ni * 16 + fr;
#pragma unroll
      for (int r = 0; r < 4; r++) yp[(size_t)r * ldy] = acc[mi][ni][r];
    }
}

// ---------------- K2: per-chunk state sums (unchanged) ----------------
template <int FG>
__device__ __forceinline__ void chunk_loop(float (&acc)[69],
                                           const float (*kk)[16],
                                           const float (*vv)[64], int e) {
  for (int m = 0; m < CH; m++) {
    float kr[16];
#pragma unroll
    for (int i = 0; i < 16; i++) kr[i] = kk[m][i];
    const float vr = vv[m][e];
    float kv[16], p[16];
#pragma unroll
    for (int i = 0; i < 16; i++) kv[i] = kr[i] * vr;
#pragma unroll
    for (int i = 0; i < 16; i++) p[i] = kr[i] * C2f;
#pragma unroll
    for (int i = 0; i < 69; i++) {
      const int f = FG + 4 * i;
      if (f >= DEXP) break;
      if (f == 0)
        acc[i] += vr;
      else if (f <= 16)
        acc[i] += 0.5f * kv[f - 1];
      else
        acc[i] += p[(f - 17) >> 4] * kv[(f - 17) & 15];
    }
  }
}

__global__ __launch_bounds__(256) void chunk_sum_kernel(
    const float* __restrict__ qkv, float* __restrict__ csS,
    float* __restrict__ csk) {
  const int blk = blockIdx.x;
  const int bh = blk >> 4, c = blk & 15;
  const int b = bh / HH, h = bh % HH;
  __shared__ float kk[CH][16];
  __shared__ float vv[CH][64];
  const float* base = qkv + (size_t)(b * LL + c * CH) * 1152;
  for (int idx = threadIdx.x; idx < CH * 16; idx += 256) {
    int m = idx >> 4, i = idx & 15;
    kk[m][i] = base[(size_t)m * 1152 + 192 + h * 16 + i];
  }
  for (int idx = threadIdx.x; idx < CH * 64; idx += 256) {
    int m = idx >> 6, e2 = idx & 63;
    vv[m][e2] = base[(size_t)m * 1152 + 384 + h * 64 + e2];
  }
  __syncthreads();
  const int e = threadIdx.x & 63, fg = threadIdx.x >> 6;
  float acc[69];
#pragma unroll
  for (int i = 0; i < 69; i++) acc[i] = 0.0f;
  switch (fg) {
    case 0: chunk_loop<0>(acc, kk, vv, e); break;
    case 1: chunk_loop<1>(acc, kk, vv, e); break;
    case 2: chunk_loop<2>(acc, kk, vv, e); break;
    default: chunk_loop<3>(acc, kk, vv, e); break;
  }
  float* S = csS + (size_t)blk * DEXP * 64;
#pragma unroll
  for (int i = 0; i < 69; i++) {
    int f = fg + 4 * i;
    if (f < DEXP) S[(size_t)f * 64 + e] = acc[i];
  }
  for (int f = threadIdx.x; f < DEXP; f += 256) {
    float s = 0.0f;
    if (f == 0) {
      s = (float)CH;
    } else if (f <= 16) {
      for (int m = 0; m < CH; m++) s += kk[m][f - 1];
      s *= 0.5f;
    } else {
      int idx = f - 17, ia = idx >> 4, ib = idx & 15;
      for (int m = 0; m < CH; m++) s += kk[m][ia] * kk[m][ib];
      s *= C2f;
    }
    csk[(size_t)blk * DEXP + f] = s;
  }
}

// ---------------- K3: across-chunk scan ----------------
__global__ __launch_bounds__(256) void prefix_kernel(float* __restrict__ csS,
                                                     float* __restrict__ csk) {
  const int gid = blockIdx.x * 256 + threadIdx.x;
  const int totS = NBH * DEXP * 64;
  if (gid < totS) {
    const int bh = gid / (DEXP * 64);
    const int idx = gid % (DEXP * 64);
    float r[NC];
    float tot = 0.0f;
#pragma unroll
    for (int c = 0; c < NC; c++) {
      r[c] = csS[(size_t)(bh * NC + c) * DEXP * 64 + idx];
      tot += r[c];
    }
    float run = 0.0f;
#pragma unroll
    for (int c = 0; c < NC; c++) {
      csS[(size_t)(bh * NC + c) * DEXP * 64 + idx] = run + tot;
      run += r[c];
    }
  } else {
    const int g2 = gid - totS;
    if (g2 < NBH * DEXP) {
      const int bh = g2 / DEXP;
      const int f = g2 % DEXP;
      float r[NC];
      float tot = 0.0f;
#pragma unroll
      for (int c = 0; c < NC; c++) {
        r[c] = csk[(size_t)(bh * NC + c) * DEXP + f];
        tot += r[c];
      }
      float run = 0.0f;
#pragma unroll
      for (int c = 0; c < NC; c++) {
        csk[(size_t)(bh * NC + c) * DEXP + f] = run + tot;
        run += r[c];
      }
    }
  }
}

// ---------------- K4a: y_state = phi(q) @ G ----------------
// grid (NBLK, 2): block = 128 rows x 32 cols. Thread = 4 rows x 4 cols.
// phi computed inline from per-thread q registers; G double-buffered in 16-row slabs.
__global__ __launch_bounds__(256) void state_kernel(
    const float* __restrict__ qkv, const float* __restrict__ csS,
    float* __restrict__ att) {
  const int blk = blockIdx.x;
  const int E0 = blockIdx.y * 32;
  const int bh = blk >> 4, c = blk & 15;
  const int b = bh / HH, h = bh % HH;
  __shared__ float qs[CH][17];
  __shared__ float G17[17][36];
  __shared__ float Gs[2][16][36];
  const float* base = qkv + (size_t)(b * LL + c * CH) * 1152 + h * 16;
  const int tid = threadIdx.x;
  for (int idx = tid; idx < CH * 16; idx += 256) {
    int t = idx >> 4, i = idx & 15;
    qs[t][i] = base[(size_t)t * 1152 + i];
  }
  const float* Gc = csS + (size_t)blk * DEXP * 64 + E0;
  if (tid < 136) {
    int fi = tid >> 3, c4 = (tid & 7) * 4;
    *(float4*)&G17[fi][c4] = *(const float4*)(Gc + (size_t)fi * 64 + c4);
  }
  if (tid < 128) {
    int fi = tid >> 3, c4 = (tid & 7) * 4;
    *(float4*)&Gs[0][fi][c4] = *(const float4*)(Gc + (size_t)(17 + fi) * 64 + c4);
  }
  __syncthreads();
  const int tr = tid >> 3, tc4 = (tid & 7) * 4;
  float qr[4][16];
#pragma unroll
  for (int r = 0; r < 4; r++)
#pragma unroll
    for (int i = 0; i < 16; i++) qr[r][i] = qs[tr * 4 + r][i];
  float acc[4][4];
  {  // f = 0 (phi = 1)
    float g[4];
    *(float4*)g = *(const float4*)&G17[0][tc4];
#pragma unroll
    for (int r = 0; r < 4; r++)
#pragma unroll
      for (int j = 0; j < 4; j++) acc[r][j] = g[j];
  }
#pragma unroll
  for (int i = 0; i < 16; i++) {  // linear: phi = q_i/2
    float g[4];
    *(float4*)g = *(const float4*)&G17[1 + i][tc4];
#pragma unroll
    for (int r = 0; r < 4; r++) {
      const float ph = 0.5f * qr[r][i];
#pragma unroll
      for (int j = 0; j < 4; j++) acc[r][j] += ph * g[j];
    }
  }
  const int lfi = tid >> 3, lc4 = (tid & 7) * 4;
#pragma unroll
  for (int k = 0; k < 16; k++) {  // quad slabs: i = k, features 17+16k..32+16k
    float4 nxt;
    if (k < 15 && tid < 128)
      nxt = *(const float4*)(Gc + (size_t)(17 + 16 * (k + 1) + lfi) * 64 + lc4);
    float ci[4];
#pragma unroll
    for (int r = 0; r < 4; r++) ci[r] = C2f * qr[r][k];
#pragma unroll
    for (int j2 = 0; j2 < 16; j2++) {
      float g[4];
      *(float4*)g = *(const float4*)&Gs[k & 1][j2][tc4];
#pragma unroll
      for (int r = 0; r < 4; r++) {
        const float ph = ci[r] * qr[r][j2];
#pragma unroll
        for (int j = 0; j < 4; j++) acc[r][j] += ph * g[j];
      }
    }
    if (k < 15 && tid < 128) *(float4*)&Gs[(k + 1) & 1][lfi][lc4] = nxt;
    __syncthreads();
  }
  const size_t rowb = (size_t)(b * LL + c * CH) + tr * 4;
#pragma unroll
  for (int r = 0; r < 4; r++) {
    float4 w;
    w.x = acc[r][0]; w.y = acc[r][1]; w.z = acc[r][2]; w.w = acc[r][3];
    *(float4*)&att[(rowb + r) * DM + h * 64 + E0 + tc4] = w;
  }
}

// ---------------- K4b: intra-chunk causal part + denominator + final scaling ----------
// grid (NBLK, 4). 32-row tile, all 64 V columns. d_state computed here from gk.
__global__ __launch_bounds__(256) void intra_kernel(
    const float* __restrict__ qkv, const float* __restrict__ csk,
    float* __restrict__ att) {
  const int blk = blockIdx.x, tt = blockIdx.y;
  const int bh = blk >> 4, c = blk & 15;
  const int b = bh / HH, h = bh % HH;
  const int t0 = tt * 32, Mn = t0 + 32;
  __shared__ float ks[CH][17];
  __shared__ float vs[CH][68];
  __shared__ float qst[32][17];
  __shared__ float a_s[32][132];
  __shared__ float gkl[DEXP];
  __shared__ float dred[32][9];
  __shared__ float zl[32];
  const float* base = qkv + (size_t)(b * LL + c * CH) * 1152;
  const int tid = threadIdx.x;
  for (int idx = tid; idx < Mn * 16; idx += 256) {
    int m = idx >> 4, i = idx & 15;
    ks[m][i] = base[(size_t)m * 1152 + 192 + h * 16 + i];
  }
  for (int idx = tid; idx < Mn * 16; idx += 256) {
    int m = idx >> 4, e4g = (idx & 15) * 4;
    *(float4*)&vs[m][e4g] = *(const float4*)&base[(size_t)m * 1152 + 384 + h * 64 + e4g];
  }
  for (int idx = tid; idx < 32 * 16; idx += 256) {
    int t = idx >> 4, i = idx & 15;
    qst[t][i] = base[(size_t)(t0 + t) * 1152 + h * 16 + i];
  }
  for (int f = tid; f < DEXP; f += 256) gkl[f] = csk[(size_t)blk * DEXP + f];
  __syncthreads();
  for (int idx = tid; idx < 32 * CH; idx += 256) {
    const int t = idx >> 7, m = idx & 127;
    if (m < Mn) {
      float s = 0.0f;
#pragma unroll
      for (int i = 0; i < 16; i++) s += qst[t][i] * ks[m][i];
      a_s[t][m] = (m <= t0 + t) ? fmaf(s, fmaf(s, 0.03125f, 0.25f), 1.0f) : 0.0f;
    }
  }
  // d_state partials: row t = tid>>3, i-pair p = tid&7
  {
    const int t = tid >> 3, p = tid & 7;
    float part = (p == 0) ? gkl[0] : 0.0f;
#pragma unroll
    for (int ii = 0; ii < 2; ii++) {
      const int i = p * 2 + ii;
      const float qi = qst[t][i];
      part += 0.5f * qi * gkl[1 + i];
      float qsum = 0.0f;
#pragma unroll
      for (int j = 0; j < 16; j++) qsum += qst[t][j] * gkl[17 + i * 16 + j];
      part += C2f * qi * qsum;
    }
    dred[t][p] = part;
  }
  __syncthreads();
  if (tid < 32) {
    float dsum = 0.0f;
    for (int m = 0; m < Mn; m++) dsum += a_s[tid][m];
    float dstt = 0.0f;
#pragma unroll
    for (int p = 0; p < 8; p++) dstt += dred[tid][p];
    zl[tid] = 1.0f / (dstt + dsum);
  }
  __syncthreads();
  const int e4 = (tid & 15) * 4, tq = tid >> 4;  // rows t0+tq, t0+tq+16
  float ac0[4] = {0, 0, 0, 0}, ac1[4] = {0, 0, 0, 0};
  for (int m = 0; m < Mn; m++) {
    float v4[4];
    *(float4*)v4 = *(const float4*)&vs[m][e4];
    const float a0 = a_s[tq][m], a1 = a_s[tq + 16][m];
#pragma unroll
    for (int j = 0; j < 4; j++) { ac0[j] += a0 * v4[j]; ac1[j] += a1 * v4[j]; }
  }
  const float z0 = zl[tq], z1 = zl[tq + 16];
  float* o0 = att + (size_t)(b * LL + c * CH + t0 + tq) * DM + h * 64 + e4;
  float* o1 = att + (size_t)(b * LL + c * CH + t0 + tq + 16) * DM + h * 64 + e4;
  float4 y0 = *(const float4*)o0;
  float4 y1 = *(const float4*)o1;
  float4 w0, w1;
  w0.x = (y0.x + ac0[0]) * z0; w0.y = (y0.y + ac0[1]) * z0;
  w0.z = (y0.z + ac0[2]) * z0; w0.w = (y0.w + ac0[3]) * z0;
  w1.x = (y1.x + ac1[0]) * z1; w1.y = (y1.y + ac1[1]) * z1;
  w1.z = (y1.z + ac1[2]) * z1; w1.w = (y1.w + ac1[3]) * z1;
  *(float4*)o0 = w0;
  *(float4*)o1 = w1;
}

extern "C" void kernel_launch(void* const* d_in, const int* in_sizes, int n_in,
                              void* d_out, int out_size, void* d_ws, size_t ws_size,
                              hipStream_t stream) {
  const float* hs = (const float*)d_in[0];
  const float* Wq = (const float*)d_in[1];
  const float* Wk = (const float*)d_in[2];
  const float* Wv = (const float*)d_in[3];
  const float* Wo = (const float*)d_in[4];
  float* out = (float*)d_out;
  char* ws = (char*)d_ws;
  // layout (58,713,600 bytes used):
  float* qkv = (float*)(ws);                     // [0, 18874368)
  float* att = (float*)(ws + 18874368);          // [18874368, 31457280)
  char*  regR = ws + 31457280;                   // [31457280, 58294272): Xhat -> csS -> Ahat
  float* csS = (float*)regR;
  float* csk = (float*)(ws + 58294272);          // 419328
  ushortT* Xhat = (ushortT*)regR;                // 4096*1536*2 = 12.6 MB (dead before csS)
  ushortT* What = (ushortT*)att;                 // 1152*1536*2 = 3.5 MB (dead before att)
  ushortT* Wohat = (ushortT*)qkv;                // 768*1536*2 (written after intra)
  ushortT* Ahat = (ushortT*)regR;                // written after state+intra (csS dead)
  const dim3 thr(256);
  // 1-2) pack inputs to [hi|lo] split-bf16
  pack_a<<<3072, thr, 0, stream>>>(hs, Xhat, 4096 * 192);
  pack_w<<<864, thr, 0, stream>>>(Wq, Wk, Wv, 192, 384, What, 1152 * 192);
  // 3) fused QKV projection -> qkv fp32 [4096][1152]; 32 M-tiles x 18 N-tiles, XCD-swizzled
  mfma_gemm<<<576, thr, 0, stream>>>(Xhat, What, qkv, 1152, 18);
  // 4-7) based linear attention
  chunk_sum_kernel<<<NBLK, thr, 0, stream>>>(qkv, csS, csk);
  {
    const int tot = NBH * DEXP * 64 + NBH * DEXP;
    prefix_kernel<<<(tot + 255) / 256, thr, 0, stream>>>(csS, csk);
  }
  state_kernel<<<dim3(NBLK, 2), thr, 0, stream>>>(qkv, csS, att);
  intra_kernel<<<dim3(NBLK, 4), thr, 0, stream>>>(qkv, csk, att);
  // 8-9) pack for output projection (qkv and csS regions dead now)
  pack_w<<<576, thr, 0, stream>>>(Wo, Wo, Wo, 768, 768, Wohat, 768 * 192);
  pack_a<<<3072, thr, 0, stream>>>(att, Ahat, 4096 * 192);
  // 10) output projection: 32 M-tiles x 12 N-tiles
  mfma_gemm<<<384, thr, 0, stream>>>(Ahat, Wohat, out, DM, 12);
}

// Round 6
// 312.704 us; speedup vs baseline: 2.0148x; 2.0148x over previous
//
#include <hip/hip_runtime.h>

typedef unsigned short ushortT;
typedef __bf16 bf16x8 __attribute__((ext_vector_type(8)));
typedef float f32x4 __attribute__((ext_vector_type(4)));

// Problem constants
#define BB   2
#define LL   2048
#define DM   768
#define HH   12
#define FT   16
#define HD   64
#define DEXP 273      // 1 + 16 + 256
#define CH   128      // chunk length
#define NC   16       // chunks per sequence (LL/CH)
#define NBH  24       // BB*HH
#define NBLK 384      // NBH*NC
#define C2f  0.17677669529663687f   // 1/(4*sqrt(2))
#define KH   768      // K per half
#define KP   1536     // packed row length: [hi(768) | lo(768)]

// ---------------- split helpers ----------------
__device__ __forceinline__ void split_bf16(float x, ushortT& hi, ushortT& lo) {
  unsigned b = __float_as_uint(x);
  unsigned r = b + 0x7FFFu + ((b >> 16) & 1u);  // RNE to bf16
  hi = (ushortT)(r >> 16);
  float hf = __uint_as_float((unsigned)hi << 16);
  lo = (ushortT)(__float_as_uint(x - hf) >> 16);  // truncate
}

// X [M][768] f32 -> Xh [M][1536] bf16 = [hi | lo]
__global__ __launch_bounds__(256) void pack_a(const float* __restrict__ X,
                                              ushortT* __restrict__ Xh,
                                              int total4) {
  int g = blockIdx.x * 256 + threadIdx.x;
  if (g >= total4) return;
  int m = g / 192, k4 = (g % 192) * 4;
  float4 v = *(const float4*)(X + (size_t)m * 768 + k4);
  ushortT h[4], l[4];
  split_bf16(v.x, h[0], l[0]);
  split_bf16(v.y, h[1], l[1]);
  split_bf16(v.z, h[2], l[2]);
  split_bf16(v.w, h[3], l[3]);
  ushortT* p = Xh + (size_t)m * KP + k4;
  *(ushort4*)p = *(ushort4*)h;
  *(ushort4*)(p + KH) = *(ushort4*)l;
}

// W rows (selected from W0/W1/W2) -> Wh [N][1536] bf16 = [hi | lo]
__global__ __launch_bounds__(256) void pack_w(const float* __restrict__ W0,
                                              const float* __restrict__ W1,
                                              const float* __restrict__ W2,
                                              int n1, int n2,
                                              ushortT* __restrict__ Wh,
                                              int total4) {
  int g = blockIdx.x * 256 + threadIdx.x;
  if (g >= total4) return;
  int n = g / 192, k4 = (g % 192) * 4;
  const float* src = (n < n1 ? W0 + (size_t)n * 768
                    : n < n2 ? W1 + (size_t)(n - n1) * 768
                             : W2 + (size_t)(n - n2) * 768);
  float4 v = *(const float4*)(src + k4);
  ushortT h[4], l[4];
  split_bf16(v.x, h[0], l[0]);
  split_bf16(v.y, h[1], l[1]);
  split_bf16(v.z, h[2], l[2]);
  split_bf16(v.w, h[3], l[3]);
  ushortT* p = Wh + (size_t)n * KP + k4;
  *(ushort4*)p = *(ushort4*)h;
  *(ushort4*)(p + KH) = *(ushort4*)l;
}

// async global->LDS, 16B per lane; lds base must be wave-uniform (lane*16 implicit)
typedef const __attribute__((address_space(1))) unsigned gq_t;
typedef __attribute__((address_space(3))) unsigned lq_t;
__device__ __forceinline__ void gload_lds16(const ushortT* g, ushortT* l) {
  __builtin_amdgcn_global_load_lds((gq_t*)g, (lq_t*)l, 16, 0, 0);
}
__device__ __forceinline__ void gload_lds16f(const float* g, float* l) {
  __builtin_amdgcn_global_load_lds((gq_t*)g, (lq_t*)l, 16, 0, 0);
}

// ---------------- MFMA GEMM: Y[M][N] = A[M][KP] @ B[N][KP]^T (3-term split-bf16) -------
// 128x64 tile, 4 waves (2 in M x 2 in N), each wave 64x32 via 4x2 mfma_f32_16x16x32_bf16.
// Grid 1-D, XCD-swizzled: blk -> xcd = blk&7 gets M-tiles [xcd*mtp, (xcd+1)*mtp).
__global__ __launch_bounds__(256) void mfma_gemm(const ushortT* __restrict__ A,
                                                 const ushortT* __restrict__ B,
                                                 float* __restrict__ Y, int ldy,
                                                 int ntiles) {
  __shared__ ushortT sAh[128 * 32], sAl[128 * 32], sBh[64 * 32], sBl[64 * 32];
  const int blk = blockIdx.x;
  const int xcd = blk & 7, slot = blk >> 3;
  const int mtp = gridDim.x / (8 * ntiles);
  const int mt = xcd * mtp + slot / ntiles;
  const int nt = slot % ntiles;
  const int bm = mt * 128, bn = nt * 64;
  const int tid = threadIdx.x, wave = tid >> 6, lane = tid & 63;
  const int srow = lane >> 2, schk = (lane & 3) * 8;  // 16 rows x 4 chunks per iter
  const ushortT* gsrc;
  ushortT* lb;
  int iters;
  switch (wave) {
    case 0:  gsrc = A + (size_t)(bm + srow) * KP + schk;      lb = sAh; iters = 8; break;
    case 1:  gsrc = A + (size_t)(bm + srow) * KP + KH + schk; lb = sAl; iters = 8; break;
    case 2:  gsrc = B + (size_t)(bn + srow) * KP + schk;      lb = sBh; iters = 4; break;
    default: gsrc = B + (size_t)(bn + srow) * KP + KH + schk; lb = sBl; iters = 4; break;
  }
  const int wm = (wave & 1) * 64, wn = (wave >> 1) * 32;
  const int fr = lane & 15, quad = lane >> 4;
  f32x4 acc[4][2] = {};
  for (int k0 = 0; k0 < KH; k0 += 32) {
    __syncthreads();  // previous compute done before LDS overwrite
    for (int it = 0; it < iters; it++)
      gload_lds16(gsrc + k0 + (size_t)it * 16 * KP, lb + it * 512);
    __syncthreads();  // drains vmcnt (compiler-inserted before barrier)
    bf16x8 ah[4], al[4], bh2[2], bl2[2];
#pragma unroll
    for (int mi = 0; mi < 4; mi++) {
      ah[mi] = *(const bf16x8*)&sAh[(wm + mi * 16 + fr) * 32 + quad * 8];
      al[mi] = *(const bf16x8*)&sAl[(wm + mi * 16 + fr) * 32 + quad * 8];
    }
#pragma unroll
    for (int ni = 0; ni < 2; ni++) {
      bh2[ni] = *(const bf16x8*)&sBh[(wn + ni * 16 + fr) * 32 + quad * 8];
      bl2[ni] = *(const bf16x8*)&sBl[(wn + ni * 16 + fr) * 32 + quad * 8];
    }
#pragma unroll
    for (int mi = 0; mi < 4; mi++)
#pragma unroll
      for (int ni = 0; ni < 2; ni++) {
        acc[mi][ni] = __builtin_amdgcn_mfma_f32_16x16x32_bf16(ah[mi], bh2[ni], acc[mi][ni], 0, 0, 0);
        acc[mi][ni] = __builtin_amdgcn_mfma_f32_16x16x32_bf16(ah[mi], bl2[ni], acc[mi][ni], 0, 0, 0);
        acc[mi][ni] = __builtin_amdgcn_mfma_f32_16x16x32_bf16(al[mi], bh2[ni], acc[mi][ni], 0, 0, 0);
      }
  }
  const int orow = quad * 4;
#pragma unroll
  for (int mi = 0; mi < 4; mi++)
#pragma unroll
    for (int ni = 0; ni < 2; ni++) {
      float* yp = Y + (size_t)(bm + wm + mi * 16 + orow) * ldy + bn + wn + ni * 16 + fr;
#pragma unroll
      for (int r = 0; r < 4; r++) yp[(size_t)r * ldy] = acc[mi][ni][r];
    }
}

// ---------------- K2: per-chunk state sums (unchanged) ----------------
template <int FG>
__device__ __forceinline__ void chunk_loop(float (&acc)[69],
                                           const float (*kk)[16],
                                           const float (*vv)[64], int e) {
  for (int m = 0; m < CH; m++) {
    float kr[16];
#pragma unroll
    for (int i = 0; i < 16; i++) kr[i] = kk[m][i];
    const float vr = vv[m][e];
    float kv[16], p[16];
#pragma unroll
    for (int i = 0; i < 16; i++) kv[i] = kr[i] * vr;
#pragma unroll
    for (int i = 0; i < 16; i++) p[i] = kr[i] * C2f;
#pragma unroll
    for (int i = 0; i < 69; i++) {
      const int f = FG + 4 * i;
      if (f >= DEXP) break;
      if (f == 0)
        acc[i] += vr;
      else if (f <= 16)
        acc[i] += 0.5f * kv[f - 1];
      else
        acc[i] += p[(f - 17) >> 4] * kv[(f - 17) & 15];
    }
  }
}

__global__ __launch_bounds__(256) void chunk_sum_kernel(
    const float* __restrict__ qkv, float* __restrict__ csS,
    float* __restrict__ csk) {
  const int blk = blockIdx.x;
  const int bh = blk >> 4, c = blk & 15;
  const int b = bh / HH, h = bh % HH;
  __shared__ float kk[CH][16];
  __shared__ float vv[CH][64];
  const float* base = qkv + (size_t)(b * LL + c * CH) * 1152;
  for (int idx = threadIdx.x; idx < CH * 16; idx += 256) {
    int m = idx >> 4, i = idx & 15;
    kk[m][i] = base[(size_t)m * 1152 + 192 + h * 16 + i];
  }
  for (int idx = threadIdx.x; idx < CH * 64; idx += 256) {
    int m = idx >> 6, e2 = idx & 63;
    vv[m][e2] = base[(size_t)m * 1152 + 384 + h * 64 + e2];
  }
  __syncthreads();
  const int e = threadIdx.x & 63, fg = threadIdx.x >> 6;
  float acc[69];
#pragma unroll
  for (int i = 0; i < 69; i++) acc[i] = 0.0f;
  switch (fg) {
    case 0: chunk_loop<0>(acc, kk, vv, e); break;
    case 1: chunk_loop<1>(acc, kk, vv, e); break;
    case 2: chunk_loop<2>(acc, kk, vv, e); break;
    default: chunk_loop<3>(acc, kk, vv, e); break;
  }
  float* S = csS + (size_t)blk * DEXP * 64;
#pragma unroll
  for (int i = 0; i < 69; i++) {
    int f = fg + 4 * i;
    if (f < DEXP) S[(size_t)f * 64 + e] = acc[i];
  }
  for (int f = threadIdx.x; f < DEXP; f += 256) {
    float s = 0.0f;
    if (f == 0) {
      s = (float)CH;
    } else if (f <= 16) {
      for (int m = 0; m < CH; m++) s += kk[m][f - 1];
      s *= 0.5f;
    } else {
      int idx = f - 17, ia = idx >> 4, ib = idx & 15;
      for (int m = 0; m < CH; m++) s += kk[m][ia] * kk[m][ib];
      s *= C2f;
    }
    csk[(size_t)blk * DEXP + f] = s;
  }
}

// ---------------- K3: across-chunk scan ----------------
__global__ __launch_bounds__(256) void prefix_kernel(float* __restrict__ csS,
                                                     float* __restrict__ csk) {
  const int gid = blockIdx.x * 256 + threadIdx.x;
  const int totS = NBH * DEXP * 64;
  if (gid < totS) {
    const int bh = gid / (DEXP * 64);
    const int idx = gid % (DEXP * 64);
    float r[NC];
    float tot = 0.0f;
#pragma unroll
    for (int c = 0; c < NC; c++) {
      r[c] = csS[(size_t)(bh * NC + c) * DEXP * 64 + idx];
      tot += r[c];
    }
    float run = 0.0f;
#pragma unroll
    for (int c = 0; c < NC; c++) {
      csS[(size_t)(bh * NC + c) * DEXP * 64 + idx] = run + tot;
      run += r[c];
    }
  } else {
    const int g2 = gid - totS;
    if (g2 < NBH * DEXP) {
      const int bh = g2 / DEXP;
      const int f = g2 % DEXP;
      float r[NC];
      float tot = 0.0f;
#pragma unroll
      for (int c = 0; c < NC; c++) {
        r[c] = csk[(size_t)(bh * NC + c) * DEXP + f];
        tot += r[c];
      }
      float run = 0.0f;
#pragma unroll
      for (int c = 0; c < NC; c++) {
        csk[(size_t)(bh * NC + c) * DEXP + f] = run + tot;
        run += r[c];
      }
    }
  }
}

// ---------------- K4a: y_state = phi(q) @ G ----------------
// grid (NBLK, 2): block = 128 rows x 32 cols. Thread = 2 rows x 8 cols.
// qr[2][16]=32 regs + acc[2][8]=16 regs; launch_bounds(256,4) caps VGPR at 128
// (R5 lesson: qr[4][16] + full unroll -> 256 VGPR + scratch spills).
// G slabs staged by async global_load_lds (zero VGPR), double-buffered.
__global__ __launch_bounds__(256, 4) void state_kernel(
    const float* __restrict__ qkv, const float* __restrict__ csS,
    float* __restrict__ att) {
  const int blk = blockIdx.x;
  const int E0 = blockIdx.y * 32;
  const int bh = blk >> 4, c = blk & 15;
  const int b = bh / HH, h = bh % HH;
  __shared__ float qs[CH][17];
  __shared__ float G17[17][36];
  __shared__ float Gs[2][16][32];
  const float* base = qkv + (size_t)(b * LL + c * CH) * 1152 + h * 16;
  const int tid = threadIdx.x;
  const int wv = tid >> 6, ln = tid & 63;
  const float* Gc = csS + (size_t)blk * DEXP * 64 + E0;  // row stride 64
  // async prefetch: slab 0 (features 17..32) -> Gs[0]; waves 0,1 cover 16x32 floats
  const int prow = wv * 8 + (ln >> 3), pc4 = (ln & 7) * 4;  // wv<2 only
  if (wv < 2)
    gload_lds16f(Gc + (size_t)(17 + prow) * 64 + pc4, &Gs[0][wv * 8][0]);
  for (int idx = tid; idx < CH * 16; idx += 256) {
    int t = idx >> 4, i = idx & 15;
    qs[t][i] = base[(size_t)t * 1152 + i];
  }
  if (tid < 136) {
    int fi = tid >> 3, c4 = (tid & 7) * 4;
    *(float4*)&G17[fi][c4] = *(const float4*)(Gc + (size_t)fi * 64 + c4);
  }
  __syncthreads();  // qs/G17 visible; drains vmcnt -> Gs[0] ready
  const int rg = tid >> 2, cg8 = (tid & 3) * 8;  // rows 2rg..2rg+1, cols cg8..cg8+7
  float qr[2][16];
#pragma unroll
  for (int r = 0; r < 2; r++)
#pragma unroll
    for (int i = 0; i < 16; i++) qr[r][i] = qs[2 * rg + r][i];
  float acc[2][8];
  {  // f = 0 (phi = 1)
    float g[8];
    *(float4*)g = *(const float4*)&G17[0][cg8];
    *(float4*)(g + 4) = *(const float4*)&G17[0][cg8 + 4];
#pragma unroll
    for (int r = 0; r < 2; r++)
#pragma unroll
      for (int j = 0; j < 8; j++) acc[r][j] = g[j];
  }
#pragma unroll
  for (int i = 0; i < 16; i++) {  // linear: phi = q_i/2
    float g[8];
    *(float4*)g = *(const float4*)&G17[1 + i][cg8];
    *(float4*)(g + 4) = *(const float4*)&G17[1 + i][cg8 + 4];
    const float pa = 0.5f * qr[0][i], pb = 0.5f * qr[1][i];
#pragma unroll
    for (int j = 0; j < 8; j++) { acc[0][j] += pa * g[j]; acc[1][j] += pb * g[j]; }
  }
#pragma unroll 1
  for (int k = 0; k < 16; k++) {  // quad slabs: i = k, features 17+16k..32+16k
    if (k < 15 && wv < 2)
      gload_lds16f(Gc + (size_t)(17 + 16 * (k + 1) + prow) * 64 + pc4,
                   &Gs[(k + 1) & 1][wv * 8][0]);
    const float cA = C2f * qr[0][k], cB = C2f * qr[1][k];
#pragma unroll
    for (int j2 = 0; j2 < 16; j2++) {
      float g[8];
      *(float4*)g = *(const float4*)&Gs[k & 1][j2][cg8];
      *(float4*)(g + 4) = *(const float4*)&Gs[k & 1][j2][cg8 + 4];
      const float pa = cA * qr[0][j2], pb = cB * qr[1][j2];
#pragma unroll
      for (int j = 0; j < 8; j++) { acc[0][j] += pa * g[j]; acc[1][j] += pb * g[j]; }
    }
    __syncthreads();  // all waves done with Gs[k&1]; drains prefetch into Gs[(k+1)&1]
  }
  const size_t rowb = (size_t)(b * LL + c * CH) + 2 * rg;
#pragma unroll
  for (int r = 0; r < 2; r++) {
    float* op = att + (rowb + r) * DM + h * 64 + E0 + cg8;
    float4 w0, w1;
    w0.x = acc[r][0]; w0.y = acc[r][1]; w0.z = acc[r][2]; w0.w = acc[r][3];
    w1.x = acc[r][4]; w1.y = acc[r][5]; w1.z = acc[r][6]; w1.w = acc[r][7];
    *(float4*)op = w0;
    *(float4*)(op + 4) = w1;
  }
}

// ---------------- K4b: intra-chunk causal part + denominator + final scaling ----------
// grid (NBLK, 4). 32-row tile, all 64 V columns. d_state computed here from gk.
__global__ __launch_bounds__(256) void intra_kernel(
    const float* __restrict__ qkv, const float* __restrict__ csk,
    float* __restrict__ att) {
  const int blk = blockIdx.x, tt = blockIdx.y;
  const int bh = blk >> 4, c = blk & 15;
  const int b = bh / HH, h = bh % HH;
  const int t0 = tt * 32, Mn = t0 + 32;
  __shared__ float ks[CH][17];
  __shared__ float vs[CH][68];
  __shared__ float qst[32][17];
  __shared__ float a_s[32][132];
  __shared__ float gkl[DEXP];
  __shared__ float dred[32][9];
  __shared__ float zl[32];
  const float* base = qkv + (size_t)(b * LL + c * CH) * 1152;
  const int tid = threadIdx.x;
  for (int idx = tid; idx < Mn * 16; idx += 256) {
    int m = idx >> 4, i = idx & 15;
    ks[m][i] = base[(size_t)m * 1152 + 192 + h * 16 + i];
  }
  for (int idx = tid; idx < Mn * 16; idx += 256) {
    int m = idx >> 4, e4g = (idx & 15) * 4;
    *(float4*)&vs[m][e4g] = *(const float4*)&base[(size_t)m * 1152 + 384 + h * 64 + e4g];
  }
  for (int idx = tid; idx < 32 * 16; idx += 256) {
    int t = idx >> 4, i = idx & 15;
    qst[t][i] = base[(size_t)(t0 + t) * 1152 + h * 16 + i];
  }
  for (int f = tid; f < DEXP; f += 256) gkl[f] = csk[(size_t)blk * DEXP + f];
  __syncthreads();
  for (int idx = tid; idx < 32 * CH; idx += 256) {
    const int t = idx >> 7, m = idx & 127;
    if (m < Mn) {
      float s = 0.0f;
#pragma unroll
      for (int i = 0; i < 16; i++) s += qst[t][i] * ks[m][i];
      a_s[t][m] = (m <= t0 + t) ? fmaf(s, fmaf(s, 0.03125f, 0.25f), 1.0f) : 0.0f;
    }
  }
  // d_state partials: row t = tid>>3, i-pair p = tid&7
  {
    const int t = tid >> 3, p = tid & 7;
    float part = (p == 0) ? gkl[0] : 0.0f;
#pragma unroll
    for (int ii = 0; ii < 2; ii++) {
      const int i = p * 2 + ii;
      const float qi = qst[t][i];
      part += 0.5f * qi * gkl[1 + i];
      float qsum = 0.0f;
#pragma unroll
      for (int j = 0; j < 16; j++) qsum += qst[t][j] * gkl[17 + i * 16 + j];
      part += C2f * qi * qsum;
    }
    dred[t][p] = part;
  }
  __syncthreads();
  if (tid < 32) {
    float dsum = 0.0f;
    for (int m = 0; m < Mn; m++) dsum += a_s[tid][m];
    float dstt = 0.0f;
#pragma unroll
    for (int p = 0; p < 8; p++) dstt += dred[tid][p];
    zl[tid] = 1.0f / (dstt + dsum);
  }
  __syncthreads();
  const int e4 = (tid & 15) * 4, tq = tid >> 4;  // rows t0+tq, t0+tq+16
  float ac0[4] = {0, 0, 0, 0}, ac1[4] = {0, 0, 0, 0};
  for (int m = 0; m < Mn; m++) {
    float v4[4];
    *(float4*)v4 = *(const float4*)&vs[m][e4];
    const float a0 = a_s[tq][m], a1 = a_s[tq + 16][m];
#pragma unroll
    for (int j = 0; j < 4; j++) { ac0[j] += a0 * v4[j]; ac1[j] += a1 * v4[j]; }
  }
  const float z0 = zl[tq], z1 = zl[tq + 16];
  float* o0 = att + (size_t)(b * LL + c * CH + t0 + tq) * DM + h * 64 + e4;
  float* o1 = att + (size_t)(b * LL + c * CH + t0 + tq + 16) * DM + h * 64 + e4;
  float4 y0 = *(const float4*)o0;
  float4 y1 = *(const float4*)o1;
  float4 w0, w1;
  w0.x = (y0.x + ac0[0]) * z0; w0.y = (y0.y + ac0[1]) * z0;
  w0.z = (y0.z + ac0[2]) * z0; w0.w = (y0.w + ac0[3]) * z0;
  w1.x = (y1.x + ac1[0]) * z1; w1.y = (y1.y + ac1[1]) * z1;
  w1.z = (y1.z + ac1[2]) * z1; w1.w = (y1.w + ac1[3]) * z1;
  *(float4*)o0 = w0;
  *(float4*)o1 = w1;
}

extern "C" void kernel_launch(void* const* d_in, const int* in_sizes, int n_in,
                              void* d_out, int out_size, void* d_ws, size_t ws_size,
                              hipStream_t stream) {
  const float* hs = (const float*)d_in[0];
  const float* Wq = (const float*)d_in[1];
  const float* Wk = (const float*)d_in[2];
  const float* Wv = (const float*)d_in[3];
  const float* Wo = (const float*)d_in[4];
  float* out = (float*)d_out;
  char* ws = (char*)d_ws;
  // layout (58,713,600 bytes used):
  float* qkv = (float*)(ws);                     // [0, 18874368)
  float* att = (float*)(ws + 18874368);          // [18874368, 31457280)
  char*  regR = ws + 31457280;                   // [31457280, 58294272): Xhat -> csS -> Ahat
  float* csS = (float*)regR;
  float* csk = (float*)(ws + 58294272);          // 419328
  ushortT* Xhat = (ushortT*)regR;                // 4096*1536*2 = 12.6 MB (dead before csS)
  ushortT* What = (ushortT*)att;                 // 1152*1536*2 = 3.5 MB (dead before att)
  ushortT* Wohat = (ushortT*)qkv;                // 768*1536*2 (written after intra)
  ushortT* Ahat = (ushortT*)regR;                // written after state+intra (csS dead)
  const dim3 thr(256);
  // 1-2) pack inputs to [hi|lo] split-bf16
  pack_a<<<3072, thr, 0, stream>>>(hs, Xhat, 4096 * 192);
  pack_w<<<864, thr, 0, stream>>>(Wq, Wk, Wv, 192, 384, What, 1152 * 192);
  // 3) fused QKV projection -> qkv fp32 [4096][1152]; 32 M-tiles x 18 N-tiles, XCD-swizzled
  mfma_gemm<<<576, thr, 0, stream>>>(Xhat, What, qkv, 1152, 18);
  // 4-7) based linear attention
  chunk_sum_kernel<<<NBLK, thr, 0, stream>>>(qkv, csS, csk);
  {
    const int tot = NBH * DEXP * 64 + NBH * DEXP;
    prefix_kernel<<<(tot + 255) / 256, thr, 0, stream>>>(csS, csk);
  }
  state_kernel<<<dim3(NBLK, 2), thr, 0, stream>>>(qkv, csS, att);
  intra_kernel<<<dim3(NBLK, 4), thr, 0, stream>>>(qkv, csk, att);
  // 8-9) pack for output projection (qkv and csS regions dead now)
  pack_w<<<576, thr, 0, stream>>>(Wo, Wo, Wo, 768, 768, Wohat, 768 * 192);
  pack_a<<<3072, thr, 0, stream>>>(att, Ahat, 4096 * 192);
  // 10) output projection: 32 M-tiles x 12 N-tiles
  mfma_gemm<<<384, thr, 0, stream>>>(Ahat, Wohat, out, DM, 12);
}

// Round 7
// 280.819 us; speedup vs baseline: 2.2436x; 1.1135x over previous
//
#include <hip/hip_runtime.h>

typedef unsigned short ushortT;
typedef __bf16 bf16x8 __attribute__((ext_vector_type(8)));
typedef float f32x4 __attribute__((ext_vector_type(4)));

// Problem constants
#define BB   2
#define LL   2048
#define DM   768
#define HH   12
#define FT   16
#define HD   64
#define DEXP 273      // 1 + 16 + 256
#define CH   128      // chunk length
#define NC   16       // chunks per sequence (LL/CH)
#define NBH  24       // BB*HH
#define NBLK 384      // NBH*NC
#define C2f  0.17677669529663687f   // 1/(4*sqrt(2))
#define KH   768      // K per half
#define KP   1536     // packed row length: [hi(768) | lo(768)]

// ---------------- split helpers ----------------
__device__ __forceinline__ void split_bf16(float x, ushortT& hi, ushortT& lo) {
  unsigned b = __float_as_uint(x);
  unsigned r = b + 0x7FFFu + ((b >> 16) & 1u);  // RNE to bf16
  hi = (ushortT)(r >> 16);
  float hf = __uint_as_float((unsigned)hi << 16);
  lo = (ushortT)(__float_as_uint(x - hf) >> 16);  // truncate
}

// X [M][768] f32 -> Xh [M][1536] bf16 = [hi | lo]
__global__ __launch_bounds__(256) void pack_a(const float* __restrict__ X,
                                              ushortT* __restrict__ Xh,
                                              int total4) {
  int g = blockIdx.x * 256 + threadIdx.x;
  if (g >= total4) return;
  int m = g / 192, k4 = (g % 192) * 4;
  float4 v = *(const float4*)(X + (size_t)m * 768 + k4);
  ushortT h[4], l[4];
  split_bf16(v.x, h[0], l[0]);
  split_bf16(v.y, h[1], l[1]);
  split_bf16(v.z, h[2], l[2]);
  split_bf16(v.w, h[3], l[3]);
  ushortT* p = Xh + (size_t)m * KP + k4;
  *(ushort4*)p = *(ushort4*)h;
  *(ushort4*)(p + KH) = *(ushort4*)l;
}

// W rows (selected from W0/W1/W2) -> Wh [N][1536] bf16 = [hi | lo]
__global__ __launch_bounds__(256) void pack_w(const float* __restrict__ W0,
                                              const float* __restrict__ W1,
                                              const float* __restrict__ W2,
                                              int n1, int n2,
                                              ushortT* __restrict__ Wh,
                                              int total4) {
  int g = blockIdx.x * 256 + threadIdx.x;
  if (g >= total4) return;
  int n = g / 192, k4 = (g % 192) * 4;
  const float* src = (n < n1 ? W0 + (size_t)n * 768
                    : n < n2 ? W1 + (size_t)(n - n1) * 768
                             : W2 + (size_t)(n - n2) * 768);
  float4 v = *(const float4*)(src + k4);
  ushortT h[4], l[4];
  split_bf16(v.x, h[0], l[0]);
  split_bf16(v.y, h[1], l[1]);
  split_bf16(v.z, h[2], l[2]);
  split_bf16(v.w, h[3], l[3]);
  ushortT* p = Wh + (size_t)n * KP + k4;
  *(ushort4*)p = *(ushort4*)h;
  *(ushort4*)(p + KH) = *(ushort4*)l;
}

// async global->LDS, 16B per lane; lds base must be wave-uniform (lane*16 implicit)
typedef const __attribute__((address_space(1))) unsigned gq_t;
typedef __attribute__((address_space(3))) unsigned lq_t;
__device__ __forceinline__ void gload_lds16(const ushortT* g, ushortT* l) {
  __builtin_amdgcn_global_load_lds((gq_t*)g, (lq_t*)l, 16, 0, 0);
}

// ---------------- MFMA GEMM: Y[M][N] = A[M][KP] @ B[N][KP]^T (3-term split-bf16) -------
// 128x64 tile, 4 waves (2 in M x 2 in N), each wave 64x32 via 4x2 mfma_f32_16x16x32_bf16.
__global__ __launch_bounds__(256) void mfma_gemm(const ushortT* __restrict__ A,
                                                 const ushortT* __restrict__ B,
                                                 float* __restrict__ Y, int ldy,
                                                 int ntiles) {
  __shared__ ushortT sAh[128 * 32], sAl[128 * 32], sBh[64 * 32], sBl[64 * 32];
  const int blk = blockIdx.x;
  const int xcd = blk & 7, slot = blk >> 3;
  const int mtp = gridDim.x / (8 * ntiles);
  const int mt = xcd * mtp + slot / ntiles;
  const int nt = slot % ntiles;
  const int bm = mt * 128, bn = nt * 64;
  const int tid = threadIdx.x, wave = tid >> 6, lane = tid & 63;
  const int srow = lane >> 2, schk = (lane & 3) * 8;
  const ushortT* gsrc;
  ushortT* lb;
  int iters;
  switch (wave) {
    case 0:  gsrc = A + (size_t)(bm + srow) * KP + schk;      lb = sAh; iters = 8; break;
    case 1:  gsrc = A + (size_t)(bm + srow) * KP + KH + schk; lb = sAl; iters = 8; break;
    case 2:  gsrc = B + (size_t)(bn + srow) * KP + schk;      lb = sBh; iters = 4; break;
    default: gsrc = B + (size_t)(bn + srow) * KP + KH + schk; lb = sBl; iters = 4; break;
  }
  const int wm = (wave & 1) * 64, wn = (wave >> 1) * 32;
  const int fr = lane & 15, quad = lane >> 4;
  f32x4 acc[4][2] = {};
  for (int k0 = 0; k0 < KH; k0 += 32) {
    __syncthreads();
    for (int it = 0; it < iters; it++)
      gload_lds16(gsrc + k0 + (size_t)it * 16 * KP, lb + it * 512);
    __syncthreads();
    bf16x8 ah[4], al[4], bh2[2], bl2[2];
#pragma unroll
    for (int mi = 0; mi < 4; mi++) {
      ah[mi] = *(const bf16x8*)&sAh[(wm + mi * 16 + fr) * 32 + quad * 8];
      al[mi] = *(const bf16x8*)&sAl[(wm + mi * 16 + fr) * 32 + quad * 8];
    }
#pragma unroll
    for (int ni = 0; ni < 2; ni++) {
      bh2[ni] = *(const bf16x8*)&sBh[(wn + ni * 16 + fr) * 32 + quad * 8];
      bl2[ni] = *(const bf16x8*)&sBl[(wn + ni * 16 + fr) * 32 + quad * 8];
    }
#pragma unroll
    for (int mi = 0; mi < 4; mi++)
#pragma unroll
      for (int ni = 0; ni < 2; ni++) {
        acc[mi][ni] = __builtin_amdgcn_mfma_f32_16x16x32_bf16(ah[mi], bh2[ni], acc[mi][ni], 0, 0, 0);
        acc[mi][ni] = __builtin_amdgcn_mfma_f32_16x16x32_bf16(ah[mi], bl2[ni], acc[mi][ni], 0, 0, 0);
        acc[mi][ni] = __builtin_amdgcn_mfma_f32_16x16x32_bf16(al[mi], bh2[ni], acc[mi][ni], 0, 0, 0);
      }
  }
  const int orow = quad * 4;
#pragma unroll
  for (int mi = 0; mi < 4; mi++)
#pragma unroll
    for (int ni = 0; ni < 2; ni++) {
      float* yp = Y + (size_t)(bm + wm + mi * 16 + orow) * ldy + bn + wn + ni * 16 + fr;
#pragma unroll
      for (int r = 0; r < 4; r++) yp[(size_t)r * ldy] = acc[mi][ni][r];
    }
}

// ---------------- K2: per-chunk state sums (unchanged) ----------------
template <int FG>
__device__ __forceinline__ void chunk_loop(float (&acc)[69],
                                           const float (*kk)[16],
                                           const float (*vv)[64], int e) {
  for (int m = 0; m < CH; m++) {
    float kr[16];
#pragma unroll
    for (int i = 0; i < 16; i++) kr[i] = kk[m][i];
    const float vr = vv[m][e];
    float kv[16], p[16];
#pragma unroll
    for (int i = 0; i < 16; i++) kv[i] = kr[i] * vr;
#pragma unroll
    for (int i = 0; i < 16; i++) p[i] = kr[i] * C2f;
#pragma unroll
    for (int i = 0; i < 69; i++) {
      const int f = FG + 4 * i;
      if (f >= DEXP) break;
      if (f == 0)
        acc[i] += vr;
      else if (f <= 16)
        acc[i] += 0.5f * kv[f - 1];
      else
        acc[i] += p[(f - 17) >> 4] * kv[(f - 17) & 15];
    }
  }
}

__global__ __launch_bounds__(256) void chunk_sum_kernel(
    const float* __restrict__ qkv, float* __restrict__ csS,
    float* __restrict__ csk) {
  const int blk = blockIdx.x;
  const int bh = blk >> 4, c = blk & 15;
  const int b = bh / HH, h = bh % HH;
  __shared__ float kk[CH][16];
  __shared__ float vv[CH][64];
  const float* base = qkv + (size_t)(b * LL + c * CH) * 1152;
  for (int idx = threadIdx.x; idx < CH * 16; idx += 256) {
    int m = idx >> 4, i = idx & 15;
    kk[m][i] = base[(size_t)m * 1152 + 192 + h * 16 + i];
  }
  for (int idx = threadIdx.x; idx < CH * 64; idx += 256) {
    int m = idx >> 6, e2 = idx & 63;
    vv[m][e2] = base[(size_t)m * 1152 + 384 + h * 64 + e2];
  }
  __syncthreads();
  const int e = threadIdx.x & 63, fg = threadIdx.x >> 6;
  float acc[69];
#pragma unroll
  for (int i = 0; i < 69; i++) acc[i] = 0.0f;
  switch (fg) {
    case 0: chunk_loop<0>(acc, kk, vv, e); break;
    case 1: chunk_loop<1>(acc, kk, vv, e); break;
    case 2: chunk_loop<2>(acc, kk, vv, e); break;
    default: chunk_loop<3>(acc, kk, vv, e); break;
  }
  float* S = csS + (size_t)blk * DEXP * 64;
#pragma unroll
  for (int i = 0; i < 69; i++) {
    int f = fg + 4 * i;
    if (f < DEXP) S[(size_t)f * 64 + e] = acc[i];
  }
  for (int f = threadIdx.x; f < DEXP; f += 256) {
    float s = 0.0f;
    if (f == 0) {
      s = (float)CH;
    } else if (f <= 16) {
      for (int m = 0; m < CH; m++) s += kk[m][f - 1];
      s *= 0.5f;
    } else {
      int idx = f - 17, ia = idx >> 4, ib = idx & 15;
      for (int m = 0; m < CH; m++) s += kk[m][ia] * kk[m][ib];
      s *= C2f;
    }
    csk[(size_t)blk * DEXP + f] = s;
  }
}

// ---------------- K3: across-chunk scan ----------------
__global__ __launch_bounds__(256) void prefix_kernel(float* __restrict__ csS,
                                                     float* __restrict__ csk) {
  const int gid = blockIdx.x * 256 + threadIdx.x;
  const int totS = NBH * DEXP * 64;
  if (gid < totS) {
    const int bh = gid / (DEXP * 64);
    const int idx = gid % (DEXP * 64);
    float r[NC];
    float tot = 0.0f;
#pragma unroll
    for (int c = 0; c < NC; c++) {
      r[c] = csS[(size_t)(bh * NC + c) * DEXP * 64 + idx];
      tot += r[c];
    }
    float run = 0.0f;
#pragma unroll
    for (int c = 0; c < NC; c++) {
      csS[(size_t)(bh * NC + c) * DEXP * 64 + idx] = run + tot;
      run += r[c];
    }
  } else {
    const int g2 = gid - totS;
    if (g2 < NBH * DEXP) {
      const int bh = g2 / DEXP;
      const int f = g2 % DEXP;
      float r[NC];
      float tot = 0.0f;
#pragma unroll
      for (int c = 0; c < NC; c++) {
        r[c] = csk[(size_t)(bh * NC + c) * DEXP + f];
        tot += r[c];
      }
      float run = 0.0f;
#pragma unroll
      for (int c = 0; c < NC; c++) {
        csk[(size_t)(bh * NC + c) * DEXP + f] = run + tot;
        run += r[c];
      }
    }
  }
}

// ---------------- K4a: y_state = phi(q) @ G via MFMA (split-bf16 3-term) ----------------
// grid (NBLK). Per block: [128 rows x 273 K] @ [273 K x 64 cols], 9 K-slabs of 32.
// phi built inline from per-thread q registers -> LDS A-layout [128][hi32|lo32].
// G staged from csS [f][e] with in-LDS transpose -> B-layout [64][hi32|lo32].
// R6 lesson: scalar-FMA version is DS-pipe-bound 3:1; MFMA moves flow to 1 b128/8192 MACs.
__global__ __launch_bounds__(256, 2) void state_kernel(
    const float* __restrict__ qkv, const float* __restrict__ csS,
    float* __restrict__ att) {
  const int blk = blockIdx.x;
  const int bh = blk >> 4, c = blk & 15;
  const int b = bh / HH, h = bh % HH;
  __shared__ ushortT phiA[2][128][72];  // stride 72 (144B): 16B-aligned, bank-spread
  __shared__ ushortT Gt[2][64][72];
  const int tid = threadIdx.x;
  const int wv = tid >> 6, lane = tid & 63;
  // per-thread q row (2 threads per row; each thread owns 16 features per slab)
  const int prow = tid >> 1, phalf = tid & 1;
  const float* qrow = qkv + (size_t)(b * LL + c * CH + prow) * 1152 + h * 16;
  float qr[16];
#pragma unroll
  for (int i = 0; i < 4; i++) {
    float4 v = *(const float4*)(qrow + i * 4);
    qr[i * 4 + 0] = v.x; qr[i * 4 + 1] = v.y;
    qr[i * 4 + 2] = v.z; qr[i * 4 + 3] = v.w;
  }
  const float* Gc = csS + (size_t)blk * DEXP * 64;
  const int gfi = tid >> 4, gn4 = (tid & 15) * 4;

#define STAGE_SLAB(S, BB)                                                     \
  {                                                                           \
    const int f0 = (S) * 32;                                                  \
    _Pragma("unroll")                                                         \
    for (int p = 0; p < 2; p++) {                                             \
      const int fi = gfi + p * 16;                                            \
      const int f = f0 + fi;                                                  \
      float4 g = make_float4(0.f, 0.f, 0.f, 0.f);                             \
      if (f < DEXP) g = *(const float4*)(Gc + (size_t)f * 64 + gn4);          \
      ushortT gh[4], gl[4];                                                   \
      split_bf16(g.x, gh[0], gl[0]);                                          \
      split_bf16(g.y, gh[1], gl[1]);                                          \
      split_bf16(g.z, gh[2], gl[2]);                                          \
      split_bf16(g.w, gh[3], gl[3]);                                          \
      _Pragma("unroll")                                                       \
      for (int j = 0; j < 4; j++) {                                           \
        Gt[BB][gn4 + j][fi] = gh[j];                                          \
        Gt[BB][gn4 + j][32 + fi] = gl[j];                                     \
      }                                                                       \
    }                                                                         \
    ushortT h16[16], l16[16];                                                 \
    _Pragma("unroll")                                                         \
    for (int j = 0; j < 16; j++) {                                            \
      const int f = f0 + phalf * 16 + j;                                      \
      float v;                                                                \
      if (f == 0) v = 1.0f;                                                   \
      else if (f < 17) v = 0.5f * qr[f - 1];                                  \
      else if (f < DEXP) {                                                    \
        int ii = f - 17;                                                      \
        v = C2f * qr[ii >> 4] * qr[ii & 15];                                  \
      } else v = 0.0f;                                                        \
      split_bf16(v, h16[j], l16[j]);                                          \
    }                                                                         \
    *(uint4*)&phiA[BB][prow][phalf * 16] = *(uint4*)&h16[0];                  \
    *(uint4*)&phiA[BB][prow][phalf * 16 + 8] = *(uint4*)&h16[8];              \
    *(uint4*)&phiA[BB][prow][32 + phalf * 16] = *(uint4*)&l16[0];             \
    *(uint4*)&phiA[BB][prow][32 + phalf * 16 + 8] = *(uint4*)&l16[8];         \
  }

  const int fr = lane & 15, quad = lane >> 4;
  f32x4 acc[2][4] = {};
  STAGE_SLAB(0, 0);
  __syncthreads();
#pragma unroll 1
  for (int s = 0; s < 9; s++) {
    if (s < 8) STAGE_SLAB(s + 1, (s + 1) & 1);
    const int bb = s & 1;
    bf16x8 ah[2], al[2];
#pragma unroll
    for (int mi = 0; mi < 2; mi++) {
      ah[mi] = *(const bf16x8*)&phiA[bb][wv * 32 + mi * 16 + fr][quad * 8];
      al[mi] = *(const bf16x8*)&phiA[bb][wv * 32 + mi * 16 + fr][32 + quad * 8];
    }
#pragma unroll
    for (int ni = 0; ni < 4; ni++) {
      bf16x8 bh2 = *(const bf16x8*)&Gt[bb][ni * 16 + fr][quad * 8];
      bf16x8 bl2 = *(const bf16x8*)&Gt[bb][ni * 16 + fr][32 + quad * 8];
#pragma unroll
      for (int mi = 0; mi < 2; mi++) {
        acc[mi][ni] = __builtin_amdgcn_mfma_f32_16x16x32_bf16(ah[mi], bh2, acc[mi][ni], 0, 0, 0);
        acc[mi][ni] = __builtin_amdgcn_mfma_f32_16x16x32_bf16(ah[mi], bl2, acc[mi][ni], 0, 0, 0);
        acc[mi][ni] = __builtin_amdgcn_mfma_f32_16x16x32_bf16(al[mi], bh2, acc[mi][ni], 0, 0, 0);
      }
    }
    __syncthreads();
  }
  const int orow = quad * 4;
#pragma unroll
  for (int mi = 0; mi < 2; mi++)
#pragma unroll
    for (int ni = 0; ni < 4; ni++) {
      float* yp = att + (size_t)(b * LL + c * CH + wv * 32 + mi * 16 + orow) * DM +
                  h * 64 + ni * 16 + fr;
#pragma unroll
      for (int r = 0; r < 4; r++) yp[(size_t)r * DM] = acc[mi][ni][r];
    }
#undef STAGE_SLAB
}

// ---------------- K4b: intra-chunk causal part + denominator + final scaling ----------
__global__ __launch_bounds__(256) void intra_kernel(
    const float* __restrict__ qkv, const float* __restrict__ csk,
    float* __restrict__ att) {
  const int blk = blockIdx.x, tt = blockIdx.y;
  const int bh = blk >> 4, c = blk & 15;
  const int b = bh / HH, h = bh % HH;
  const int t0 = tt * 32, Mn = t0 + 32;
  __shared__ float ks[CH][17];
  __shared__ float vs[CH][68];
  __shared__ float qst[32][17];
  __shared__ float a_s[32][132];
  __shared__ float gkl[DEXP];
  __shared__ float dred[32][9];
  __shared__ float zl[32];
  const float* base = qkv + (size_t)(b * LL + c * CH) * 1152;
  const int tid = threadIdx.x;
  for (int idx = tid; idx < Mn * 16; idx += 256) {
    int m = idx >> 4, i = idx & 15;
    ks[m][i] = base[(size_t)m * 1152 + 192 + h * 16 + i];
  }
  for (int idx = tid; idx < Mn * 16; idx += 256) {
    int m = idx >> 4, e4g = (idx & 15) * 4;
    *(float4*)&vs[m][e4g] = *(const float4*)&base[(size_t)m * 1152 + 384 + h * 64 + e4g];
  }
  for (int idx = tid; idx < 32 * 16; idx += 256) {
    int t = idx >> 4, i = idx & 15;
    qst[t][i] = base[(size_t)(t0 + t) * 1152 + h * 16 + i];
  }
  for (int f = tid; f < DEXP; f += 256) gkl[f] = csk[(size_t)blk * DEXP + f];
  __syncthreads();
  for (int idx = tid; idx < 32 * CH; idx += 256) {
    const int t = idx >> 7, m = idx & 127;
    if (m < Mn) {
      float s = 0.0f;
#pragma unroll
      for (int i = 0; i < 16; i++) s += qst[t][i] * ks[m][i];
      a_s[t][m] = (m <= t0 + t) ? fmaf(s, fmaf(s, 0.03125f, 0.25f), 1.0f) : 0.0f;
    }
  }
  {
    const int t = tid >> 3, p = tid & 7;
    float part = (p == 0) ? gkl[0] : 0.0f;
#pragma unroll
    for (int ii = 0; ii < 2; ii++) {
      const int i = p * 2 + ii;
      const float qi = qst[t][i];
      part += 0.5f * qi * gkl[1 + i];
      float qsum = 0.0f;
#pragma unroll
      for (int j = 0; j < 16; j++) qsum += qst[t][j] * gkl[17 + i * 16 + j];
      part += C2f * qi * qsum;
    }
    dred[t][p] = part;
  }
  __syncthreads();
  if (tid < 32) {
    float dsum = 0.0f;
    for (int m = 0; m < Mn; m++) dsum += a_s[tid][m];
    float dstt = 0.0f;
#pragma unroll
    for (int p = 0; p < 8; p++) dstt += dred[tid][p];
    zl[tid] = 1.0f / (dstt + dsum);
  }
  __syncthreads();
  const int e4 = (tid & 15) * 4, tq = tid >> 4;
  float ac0[4] = {0, 0, 0, 0}, ac1[4] = {0, 0, 0, 0};
  for (int m = 0; m < Mn; m++) {
    float v4[4];
    *(float4*)v4 = *(const float4*)&vs[m][e4];
    const float a0 = a_s[tq][m], a1 = a_s[tq + 16][m];
#pragma unroll
    for (int j = 0; j < 4; j++) { ac0[j] += a0 * v4[j]; ac1[j] += a1 * v4[j]; }
  }
  const float z0 = zl[tq], z1 = zl[tq + 16];
  float* o0 = att + (size_t)(b * LL + c * CH + t0 + tq) * DM + h * 64 + e4;
  float* o1 = att + (size_t)(b * LL + c * CH + t0 + tq + 16) * DM + h * 64 + e4;
  float4 y0 = *(const float4*)o0;
  float4 y1 = *(const float4*)o1;
  float4 w0, w1;
  w0.x = (y0.x + ac0[0]) * z0; w0.y = (y0.y + ac0[1]) * z0;
  w0.z = (y0.z + ac0[2]) * z0; w0.w = (y0.w + ac0[3]) * z0;
  w1.x = (y1.x + ac1[0]) * z1; w1.y = (y1.y + ac1[1]) * z1;
  w1.z = (y1.z + ac1[2]) * z1; w1.w = (y1.w + ac1[3]) * z1;
  *(float4*)o0 = w0;
  *(float4*)o1 = w1;
}

extern "C" void kernel_launch(void* const* d_in, const int* in_sizes, int n_in,
                              void* d_out, int out_size, void* d_ws, size_t ws_size,
                              hipStream_t stream) {
  const float* hs = (const float*)d_in[0];
  const float* Wq = (const float*)d_in[1];
  const float* Wk = (const float*)d_in[2];
  const float* Wv = (const float*)d_in[3];
  const float* Wo = (const float*)d_in[4];
  float* out = (float*)d_out;
  char* ws = (char*)d_ws;
  // layout (58,713,600 bytes used):
  float* qkv = (float*)(ws);                     // [0, 18874368)
  float* att = (float*)(ws + 18874368);          // [18874368, 31457280)
  char*  regR = ws + 31457280;                   // [31457280, 58294272): Xhat -> csS -> Ahat
  float* csS = (float*)regR;
  float* csk = (float*)(ws + 58294272);          // 419328
  ushortT* Xhat = (ushortT*)regR;                // 4096*1536*2 = 12.6 MB (dead before csS)
  ushortT* What = (ushortT*)att;                 // 1152*1536*2 = 3.5 MB (dead before att)
  ushortT* Wohat = (ushortT*)qkv;                // 768*1536*2 (written after intra)
  ushortT* Ahat = (ushortT*)regR;                // written after state+intra (csS dead)
  const dim3 thr(256);
  // 1-2) pack inputs to [hi|lo] split-bf16
  pack_a<<<3072, thr, 0, stream>>>(hs, Xhat, 4096 * 192);
  pack_w<<<864, thr, 0, stream>>>(Wq, Wk, Wv, 192, 384, What, 1152 * 192);
  // 3) fused QKV projection -> qkv fp32 [4096][1152]; 32 M-tiles x 18 N-tiles, XCD-swizzled
  mfma_gemm<<<576, thr, 0, stream>>>(Xhat, What, qkv, 1152, 18);
  // 4-7) based linear attention
  chunk_sum_kernel<<<NBLK, thr, 0, stream>>>(qkv, csS, csk);
  {
    const int tot = NBH * DEXP * 64 + NBH * DEXP;
    prefix_kernel<<<(tot + 255) / 256, thr, 0, stream>>>(csS, csk);
  }
  state_kernel<<<NBLK, thr, 0, stream>>>(qkv, csS, att);
  intra_kernel<<<dim3(NBLK, 4), thr, 0, stream>>>(qkv, csk, att);
  // 8-9) pack for output projection (qkv and csS regions dead now)
  pack_w<<<576, thr, 0, stream>>>(Wo, Wo, Wo, 768, 768, Wohat, 768 * 192);
  pack_a<<<3072, thr, 0, stream>>>(att, Ahat, 4096 * 192);
  // 10) output projection: 32 M-tiles x 12 N-tiles
  mfma_gemm<<<384, thr, 0, stream>>>(Ahat, Wohat, out, DM, 12);
}

// Round 8
// 273.463 us; speedup vs baseline: 2.3039x; 1.0269x over previous
//
#include <hip/hip_runtime.h>

typedef unsigned short ushortT;
typedef __bf16 bf16x8 __attribute__((ext_vector_type(8)));
typedef float f32x4 __attribute__((ext_vector_type(4)));

// Problem constants
#define BB   2
#define LL   2048
#define DM   768
#define HH   12
#define FT   16
#define HD   64
#define DEXP 273      // 1 + 16 + 256
#define CH   128      // chunk length
#define NC   16       // chunks per sequence (LL/CH)
#define NBH  24       // BB*HH
#define NBLK 384      // NBH*NC
#define C2f  0.17677669529663687f   // 1/(4*sqrt(2))
#define KH   768      // K per half
#define KP   1536     // packed row length: [hi(768) | lo(768)]

// ---------------- split helpers ----------------
__device__ __forceinline__ void split_bf16(float x, ushortT& hi, ushortT& lo) {
  unsigned b = __float_as_uint(x);
  unsigned r = b + 0x7FFFu + ((b >> 16) & 1u);  // RNE to bf16
  hi = (ushortT)(r >> 16);
  float hf = __uint_as_float((unsigned)hi << 16);
  lo = (ushortT)(__float_as_uint(x - hf) >> 16);  // truncate
}

// X [M][768] f32 -> Xh [M][1536] bf16 = [hi | lo]
__global__ __launch_bounds__(256) void pack_a(const float* __restrict__ X,
                                              ushortT* __restrict__ Xh,
                                              int total4) {
  int g = blockIdx.x * 256 + threadIdx.x;
  if (g >= total4) return;
  int m = g / 192, k4 = (g % 192) * 4;
  float4 v = *(const float4*)(X + (size_t)m * 768 + k4);
  ushortT h[4], l[4];
  split_bf16(v.x, h[0], l[0]);
  split_bf16(v.y, h[1], l[1]);
  split_bf16(v.z, h[2], l[2]);
  split_bf16(v.w, h[3], l[3]);
  ushortT* p = Xh + (size_t)m * KP + k4;
  *(ushort4*)p = *(ushort4*)h;
  *(ushort4*)(p + KH) = *(ushort4*)l;
}

// W rows (selected from W0/W1/W2) -> Wh [N][1536] bf16 = [hi | lo]
__global__ __launch_bounds__(256) void pack_w(const float* __restrict__ W0,
                                              const float* __restrict__ W1,
                                              const float* __restrict__ W2,
                                              int n1, int n2,
                                              ushortT* __restrict__ Wh,
                                              int total4) {
  int g = blockIdx.x * 256 + threadIdx.x;
  if (g >= total4) return;
  int n = g / 192, k4 = (g % 192) * 4;
  const float* src = (n < n1 ? W0 + (size_t)n * 768
                    : n < n2 ? W1 + (size_t)(n - n1) * 768
                             : W2 + (size_t)(n - n2) * 768);
  float4 v = *(const float4*)(src + k4);
  ushortT h[4], l[4];
  split_bf16(v.x, h[0], l[0]);
  split_bf16(v.y, h[1], l[1]);
  split_bf16(v.z, h[2], l[2]);
  split_bf16(v.w, h[3], l[3]);
  ushortT* p = Wh + (size_t)n * KP + k4;
  *(ushort4*)p = *(ushort4*)h;
  *(ushort4*)(p + KH) = *(ushort4*)l;
}

// async global->LDS, 16B per lane; lds base must be wave-uniform (lane*16 implicit)
typedef const __attribute__((address_space(1))) unsigned gq_t;
typedef __attribute__((address_space(3))) unsigned lq_t;
__device__ __forceinline__ void gload_lds16(const ushortT* g, ushortT* l) {
  __builtin_amdgcn_global_load_lds((gq_t*)g, (lq_t*)l, 16, 0, 0);
}

// ---------------- MFMA GEMM: Y[M][N] = A[M][KP] @ B[N][KP]^T (3-term split-bf16) -------
// 128x64 tile, 4 waves (2 in M x 2 in N), each wave 64x32 via 4x2 mfma_f32_16x16x32_bf16.
__global__ __launch_bounds__(256) void mfma_gemm(const ushortT* __restrict__ A,
                                                 const ushortT* __restrict__ B,
                                                 float* __restrict__ Y, int ldy,
                                                 int ntiles) {
  __shared__ ushortT sAh[128 * 32], sAl[128 * 32], sBh[64 * 32], sBl[64 * 32];
  const int blk = blockIdx.x;
  const int xcd = blk & 7, slot = blk >> 3;
  const int mtp = gridDim.x / (8 * ntiles);
  const int mt = xcd * mtp + slot / ntiles;
  const int nt = slot % ntiles;
  const int bm = mt * 128, bn = nt * 64;
  const int tid = threadIdx.x, wave = tid >> 6, lane = tid & 63;
  const int srow = lane >> 2, schk = (lane & 3) * 8;
  const ushortT* gsrc;
  ushortT* lb;
  int iters;
  switch (wave) {
    case 0:  gsrc = A + (size_t)(bm + srow) * KP + schk;      lb = sAh; iters = 8; break;
    case 1:  gsrc = A + (size_t)(bm + srow) * KP + KH + schk; lb = sAl; iters = 8; break;
    case 2:  gsrc = B + (size_t)(bn + srow) * KP + schk;      lb = sBh; iters = 4; break;
    default: gsrc = B + (size_t)(bn + srow) * KP + KH + schk; lb = sBl; iters = 4; break;
  }
  const int wm = (wave & 1) * 64, wn = (wave >> 1) * 32;
  const int fr = lane & 15, quad = lane >> 4;
  f32x4 acc[4][2] = {};
  for (int k0 = 0; k0 < KH; k0 += 32) {
    __syncthreads();
    for (int it = 0; it < iters; it++)
      gload_lds16(gsrc + k0 + (size_t)it * 16 * KP, lb + it * 512);
    __syncthreads();
    bf16x8 ah[4], al[4], bh2[2], bl2[2];
#pragma unroll
    for (int mi = 0; mi < 4; mi++) {
      ah[mi] = *(const bf16x8*)&sAh[(wm + mi * 16 + fr) * 32 + quad * 8];
      al[mi] = *(const bf16x8*)&sAl[(wm + mi * 16 + fr) * 32 + quad * 8];
    }
#pragma unroll
    for (int ni = 0; ni < 2; ni++) {
      bh2[ni] = *(const bf16x8*)&sBh[(wn + ni * 16 + fr) * 32 + quad * 8];
      bl2[ni] = *(const bf16x8*)&sBl[(wn + ni * 16 + fr) * 32 + quad * 8];
    }
#pragma unroll
    for (int mi = 0; mi < 4; mi++)
#pragma unroll
      for (int ni = 0; ni < 2; ni++) {
        acc[mi][ni] = __builtin_amdgcn_mfma_f32_16x16x32_bf16(ah[mi], bh2[ni], acc[mi][ni], 0, 0, 0);
        acc[mi][ni] = __builtin_amdgcn_mfma_f32_16x16x32_bf16(ah[mi], bl2[ni], acc[mi][ni], 0, 0, 0);
        acc[mi][ni] = __builtin_amdgcn_mfma_f32_16x16x32_bf16(al[mi], bh2[ni], acc[mi][ni], 0, 0, 0);
      }
  }
  const int orow = quad * 4;
#pragma unroll
  for (int mi = 0; mi < 4; mi++)
#pragma unroll
    for (int ni = 0; ni < 2; ni++) {
      float* yp = Y + (size_t)(bm + wm + mi * 16 + orow) * ldy + bn + wn + ni * 16 + fr;
#pragma unroll
      for (int r = 0; r < 4; r++) yp[(size_t)r * ldy] = acc[mi][ni][r];
    }
}

// ---------------- K2: csS = phi_k^T @ V via MFMA (split-bf16 3-term) ----------------
// Per block (one chunk): A = phi_k^T [288 pad f][128 m], B = V^T [64 e][128 m], 4 K-slabs
// of 32 positions. phi built inline from kT fp32 panel; csk stays scalar fp32 (reads kT).
// R7 lesson applied: this was the last scalar-FMA GEMM-in-disguise (47.5us, MfmaUtil 0).
__global__ __launch_bounds__(256, 2) void chunk_sum_kernel(
    const float* __restrict__ qkv, float* __restrict__ csS,
    float* __restrict__ csk) {
  const int blk = blockIdx.x;
  const int bh = blk >> 4, c = blk & 15;
  const int b = bh / HH, h = bh % HH;
  __shared__ float kT[16][128];         // k^T fp32, persists whole kernel (8.2 KB)
  __shared__ ushortT phiA[288][72];     // A slab: [f][hi32|lo32], stride 72 (41.5 KB)
  __shared__ ushortT Vt[64][72];        // B slab: [e][hi32|lo32] (9.2 KB)
  const float* base = qkv + (size_t)(b * LL + c * CH) * 1152;
  const int tid = threadIdx.x;
  const int wave = tid >> 6, lane = tid & 63;
  const int fr = lane & 15, quad = lane >> 4;
  // stage k^T: coalesced read k[m][i], scatter to kT[i][m]
  for (int idx = tid; idx < 512; idx += 256) {
    int m = idx >> 2, i4 = (idx & 3) * 4;
    float4 k4 = *(const float4*)&base[(size_t)m * 1152 + 192 + h * 16 + i4];
    kT[i4 + 0][m] = k4.x; kT[i4 + 1][m] = k4.y;
    kT[i4 + 2][m] = k4.z; kT[i4 + 3][m] = k4.w;
  }
  const int wm2 = (wave & 1) * 144, wn2 = (wave >> 1) * 32;
  f32x4 acc[9][2] = {};
  __syncthreads();
#pragma unroll 1
  for (int s = 0; s < 4; s++) {
    const int m0 = s * 32;
    if (s) __syncthreads();  // previous slab's MFMA done before overwrite
    // stage Vt (B operand): read V fp32 coalesced, split, transpose-scatter
    for (int idx = tid; idx < 512; idx += 256) {
      int m = m0 + (idx >> 4), e4 = (idx & 15) * 4;
      float4 v4 = *(const float4*)&base[(size_t)m * 1152 + 384 + h * 64 + e4];
      ushortT hh[4], ll[4];
      split_bf16(v4.x, hh[0], ll[0]); split_bf16(v4.y, hh[1], ll[1]);
      split_bf16(v4.z, hh[2], ll[2]); split_bf16(v4.w, hh[3], ll[3]);
      const int mi2 = m - m0;
#pragma unroll
      for (int j = 0; j < 4; j++) {
        Vt[e4 + j][mi2] = hh[j];
        Vt[e4 + j][32 + mi2] = ll[j];
      }
    }
    // stage phiA rows (A operand): row f, 32 m-positions
    for (int rr = tid; rr < 288; rr += 256) {
      const int f = rr;
      const float* pa = (f >= 17) ? kT[(f - 17) >> 4] : (f >= 1 ? kT[f - 1] : kT[0]);
      const float* pb = (f >= 17) ? kT[(f - 17) & 15] : kT[0];
      const float sc = (f == 0) ? 1.0f : (f < 17 ? 0.5f : C2f);
      const bool quadf = (f >= 17);
      const bool valid = (f < DEXP);
      ushortT hrow[32], lrow[32];
#pragma unroll
      for (int g = 0; g < 8; g++) {
        float4 a4 = *(const float4*)&pa[m0 + g * 4];
        float4 b4 = *(const float4*)&pb[m0 + g * 4];
        float v0, v1, v2, v3;
        if (f == 0) {
          v0 = v1 = v2 = v3 = 1.0f;
        } else if (!quadf) {
          v0 = sc * a4.x; v1 = sc * a4.y; v2 = sc * a4.z; v3 = sc * a4.w;
        } else {
          v0 = sc * a4.x * b4.x; v1 = sc * a4.y * b4.y;
          v2 = sc * a4.z * b4.z; v3 = sc * a4.w * b4.w;
        }
        if (!valid) { v0 = v1 = v2 = v3 = 0.0f; }
        split_bf16(v0, hrow[g * 4 + 0], lrow[g * 4 + 0]);
        split_bf16(v1, hrow[g * 4 + 1], lrow[g * 4 + 1]);
        split_bf16(v2, hrow[g * 4 + 2], lrow[g * 4 + 2]);
        split_bf16(v3, hrow[g * 4 + 3], lrow[g * 4 + 3]);
      }
      *(uint4*)&phiA[f][0] = *(uint4*)&hrow[0];
      *(uint4*)&phiA[f][8] = *(uint4*)&hrow[8];
      *(uint4*)&phiA[f][16] = *(uint4*)&hrow[16];
      *(uint4*)&phiA[f][24] = *(uint4*)&hrow[24];
      *(uint4*)&phiA[f][32] = *(uint4*)&lrow[0];
      *(uint4*)&phiA[f][40] = *(uint4*)&lrow[8];
      *(uint4*)&phiA[f][48] = *(uint4*)&lrow[16];
      *(uint4*)&phiA[f][56] = *(uint4*)&lrow[24];
    }
    __syncthreads();
    // MFMA: 9 M-tiles x 2 N-tiles x 3 terms per wave
    bf16x8 bhf[2], blf[2];
#pragma unroll
    for (int ni = 0; ni < 2; ni++) {
      bhf[ni] = *(const bf16x8*)&Vt[wn2 + ni * 16 + fr][quad * 8];
      blf[ni] = *(const bf16x8*)&Vt[wn2 + ni * 16 + fr][32 + quad * 8];
    }
#pragma unroll
    for (int mi = 0; mi < 9; mi++) {
      bf16x8 ah = *(const bf16x8*)&phiA[wm2 + mi * 16 + fr][quad * 8];
      bf16x8 al = *(const bf16x8*)&phiA[wm2 + mi * 16 + fr][32 + quad * 8];
#pragma unroll
      for (int ni = 0; ni < 2; ni++) {
        acc[mi][ni] = __builtin_amdgcn_mfma_f32_16x16x32_bf16(ah, bhf[ni], acc[mi][ni], 0, 0, 0);
        acc[mi][ni] = __builtin_amdgcn_mfma_f32_16x16x32_bf16(ah, blf[ni], acc[mi][ni], 0, 0, 0);
        acc[mi][ni] = __builtin_amdgcn_mfma_f32_16x16x32_bf16(al, bhf[ni], acc[mi][ni], 0, 0, 0);
      }
    }
  }
  // csk (fp32 exact, reads persistent kT)
  for (int f = tid; f < DEXP; f += 256) {
    float sum = 0.0f;
    if (f == 0) {
      sum = (float)CH;
    } else if (f < 17) {
      const float* p = kT[f - 1];
      for (int m = 0; m < CH; m += 4) {
        float4 x = *(const float4*)&p[m];
        sum += x.x + x.y + x.z + x.w;
      }
      sum *= 0.5f;
    } else {
      const float* pa2 = kT[(f - 17) >> 4];
      const float* pb2 = kT[(f - 17) & 15];
      for (int m = 0; m < CH; m += 4) {
        float4 x = *(const float4*)&pa2[m];
        float4 y = *(const float4*)&pb2[m];
        sum += x.x * y.x + x.y * y.y + x.z * y.z + x.w * y.w;
      }
      sum *= C2f;
    }
    csk[(size_t)blk * DEXP + f] = sum;
  }
  // epilogue: D rows = features f, cols = e (coalesced over fr)
  float* S = csS + (size_t)blk * DEXP * 64;
#pragma unroll
  for (int mi = 0; mi < 9; mi++)
#pragma unroll
    for (int ni = 0; ni < 2; ni++)
#pragma unroll
      for (int r = 0; r < 4; r++) {
        const int f = wm2 + mi * 16 + quad * 4 + r;
        if (f < DEXP) S[(size_t)f * 64 + wn2 + ni * 16 + fr] = acc[mi][ni][r];
      }
}

// ---------------- K3: across-chunk scan ----------------
__global__ __launch_bounds__(256) void prefix_kernel(float* __restrict__ csS,
                                                     float* __restrict__ csk) {
  const int gid = blockIdx.x * 256 + threadIdx.x;
  const int totS = NBH * DEXP * 64;
  if (gid < totS) {
    const int bh = gid / (DEXP * 64);
    const int idx = gid % (DEXP * 64);
    float r[NC];
    float tot = 0.0f;
#pragma unroll
    for (int c = 0; c < NC; c++) {
      r[c] = csS[(size_t)(bh * NC + c) * DEXP * 64 + idx];
      tot += r[c];
    }
    float run = 0.0f;
#pragma unroll
    for (int c = 0; c < NC; c++) {
      csS[(size_t)(bh * NC + c) * DEXP * 64 + idx] = run + tot;
      run += r[c];
    }
  } else {
    const int g2 = gid - totS;
    if (g2 < NBH * DEXP) {
      const int bh = g2 / DEXP;
      const int f = g2 % DEXP;
      float r[NC];
      float tot = 0.0f;
#pragma unroll
      for (int c = 0; c < NC; c++) {
        r[c] = csk[(size_t)(bh * NC + c) * DEXP + f];
        tot += r[c];
      }
      float run = 0.0f;
#pragma unroll
      for (int c = 0; c < NC; c++) {
        csk[(size_t)(bh * NC + c) * DEXP + f] = run + tot;
        run += r[c];
      }
    }
  }
}

// ---------------- K4a: y_state = phi(q) @ G via MFMA (split-bf16 3-term) ----------------
__global__ __launch_bounds__(256, 2) void state_kernel(
    const float* __restrict__ qkv, const float* __restrict__ csS,
    float* __restrict__ att) {
  const int blk = blockIdx.x;
  const int bh = blk >> 4, c = blk & 15;
  const int b = bh / HH, h = bh % HH;
  __shared__ ushortT phiA[2][128][72];  // stride 72 (144B): 16B-aligned, bank-spread
  __shared__ ushortT Gt[2][64][72];
  const int tid = threadIdx.x;
  const int wv = tid >> 6, lane = tid & 63;
  const int prow = tid >> 1, phalf = tid & 1;
  const float* qrow = qkv + (size_t)(b * LL + c * CH + prow) * 1152 + h * 16;
  float qr[16];
#pragma unroll
  for (int i = 0; i < 4; i++) {
    float4 v = *(const float4*)(qrow + i * 4);
    qr[i * 4 + 0] = v.x; qr[i * 4 + 1] = v.y;
    qr[i * 4 + 2] = v.z; qr[i * 4 + 3] = v.w;
  }
  const float* Gc = csS + (size_t)blk * DEXP * 64;
  const int gfi = tid >> 4, gn4 = (tid & 15) * 4;

#define STAGE_SLAB(S, BB)                                                     \
  {                                                                           \
    const int f0 = (S) * 32;                                                  \
    _Pragma("unroll")                                                         \
    for (int p = 0; p < 2; p++) {                                             \
      const int fi = gfi + p * 16;                                            \
      const int f = f0 + fi;                                                  \
      float4 g = make_float4(0.f, 0.f, 0.f, 0.f);                             \
      if (f < DEXP) g = *(const float4*)(Gc + (size_t)f * 64 + gn4);          \
      ushortT gh[4], gl[4];                                                   \
      split_bf16(g.x, gh[0], gl[0]);                                          \
      split_bf16(g.y, gh[1], gl[1]);                                          \
      split_bf16(g.z, gh[2], gl[2]);                                          \
      split_bf16(g.w, gh[3], gl[3]);                                          \
      _Pragma("unroll")                                                       \
      for (int j = 0; j < 4; j++) {                                           \
        Gt[BB][gn4 + j][fi] = gh[j];                                          \
        Gt[BB][gn4 + j][32 + fi] = gl[j];                                     \
      }                                                                       \
    }                                                                         \
    ushortT h16[16], l16[16];                                                 \
    _Pragma("unroll")                                                         \
    for (int j = 0; j < 16; j++) {                                            \
      const int f = f0 + phalf * 16 + j;                                      \
      float v;                                                                \
      if (f == 0) v = 1.0f;                                                   \
      else if (f < 17) v = 0.5f * qr[f - 1];                                  \
      else if (f < DEXP) {                                                    \
        int ii = f - 17;                                                      \
        v = C2f * qr[ii >> 4] * qr[ii & 15];                                  \
      } else v = 0.0f;                                                        \
      split_bf16(v, h16[j], l16[j]);                                          \
    }                                                                         \
    *(uint4*)&phiA[BB][prow][phalf * 16] = *(uint4*)&h16[0];                  \
    *(uint4*)&phiA[BB][prow][phalf * 16 + 8] = *(uint4*)&h16[8];              \
    *(uint4*)&phiA[BB][prow][32 + phalf * 16] = *(uint4*)&l16[0];             \
    *(uint4*)&phiA[BB][prow][32 + phalf * 16 + 8] = *(uint4*)&l16[8];         \
  }

  const int fr = lane & 15, quad = lane >> 4;
  f32x4 acc[2][4] = {};
  STAGE_SLAB(0, 0);
  __syncthreads();
#pragma unroll 1
  for (int s = 0; s < 9; s++) {
    if (s < 8) STAGE_SLAB(s + 1, (s + 1) & 1);
    const int bb = s & 1;
    bf16x8 ah[2], al[2];
#pragma unroll
    for (int mi = 0; mi < 2; mi++) {
      ah[mi] = *(const bf16x8*)&phiA[bb][wv * 32 + mi * 16 + fr][quad * 8];
      al[mi] = *(const bf16x8*)&phiA[bb][wv * 32 + mi * 16 + fr][32 + quad * 8];
    }
#pragma unroll
    for (int ni = 0; ni < 4; ni++) {
      bf16x8 bh2 = *(const bf16x8*)&Gt[bb][ni * 16 + fr][quad * 8];
      bf16x8 bl2 = *(const bf16x8*)&Gt[bb][ni * 16 + fr][32 + quad * 8];
#pragma unroll
      for (int mi = 0; mi < 2; mi++) {
        acc[mi][ni] = __builtin_amdgcn_mfma_f32_16x16x32_bf16(ah[mi], bh2, acc[mi][ni], 0, 0, 0);
        acc[mi][ni] = __builtin_amdgcn_mfma_f32_16x16x32_bf16(ah[mi], bl2, acc[mi][ni], 0, 0, 0);
        acc[mi][ni] = __builtin_amdgcn_mfma_f32_16x16x32_bf16(al[mi], bh2, acc[mi][ni], 0, 0, 0);
      }
    }
    __syncthreads();
  }
  const int orow = quad * 4;
#pragma unroll
  for (int mi = 0; mi < 2; mi++)
#pragma unroll
    for (int ni = 0; ni < 4; ni++) {
      float* yp = att + (size_t)(b * LL + c * CH + wv * 32 + mi * 16 + orow) * DM +
                  h * 64 + ni * 16 + fr;
#pragma unroll
      for (int r = 0; r < 4; r++) yp[(size_t)r * DM] = acc[mi][ni][r];
    }
#undef STAGE_SLAB
}

// ---------------- K4b: intra-chunk causal part + denominator + final scaling ----------
__global__ __launch_bounds__(256) void intra_kernel(
    const float* __restrict__ qkv, const float* __restrict__ csk,
    float* __restrict__ att) {
  const int blk = blockIdx.x, tt = blockIdx.y;
  const int bh = blk >> 4, c = blk & 15;
  const int b = bh / HH, h = bh % HH;
  const int t0 = tt * 32, Mn = t0 + 32;
  __shared__ float ks[CH][17];
  __shared__ float vs[CH][68];
  __shared__ float qst[32][17];
  __shared__ float a_s[32][132];
  __shared__ float gkl[DEXP];
  __shared__ float dred[32][9];
  __shared__ float zl[32];
  const float* base = qkv + (size_t)(b * LL + c * CH) * 1152;
  const int tid = threadIdx.x;
  for (int idx = tid; idx < Mn * 16; idx += 256) {
    int m = idx >> 4, i = idx & 15;
    ks[m][i] = base[(size_t)m * 1152 + 192 + h * 16 + i];
  }
  for (int idx = tid; idx < Mn * 16; idx += 256) {
    int m = idx >> 4, e4g = (idx & 15) * 4;
    *(float4*)&vs[m][e4g] = *(const float4*)&base[(size_t)m * 1152 + 384 + h * 64 + e4g];
  }
  for (int idx = tid; idx < 32 * 16; idx += 256) {
    int t = idx >> 4, i = idx & 15;
    qst[t][i] = base[(size_t)(t0 + t) * 1152 + h * 16 + i];
  }
  for (int f = tid; f < DEXP; f += 256) gkl[f] = csk[(size_t)blk * DEXP + f];
  __syncthreads();
  for (int idx = tid; idx < 32 * CH; idx += 256) {
    const int t = idx >> 7, m = idx & 127;
    if (m < Mn) {
      float s = 0.0f;
#pragma unroll
      for (int i = 0; i < 16; i++) s += qst[t][i] * ks[m][i];
      a_s[t][m] = (m <= t0 + t) ? fmaf(s, fmaf(s, 0.03125f, 0.25f), 1.0f) : 0.0f;
    }
  }
  {
    const int t = tid >> 3, p = tid & 7;
    float part = (p == 0) ? gkl[0] : 0.0f;
#pragma unroll
    for (int ii = 0; ii < 2; ii++) {
      const int i = p * 2 + ii;
      const float qi = qst[t][i];
      part += 0.5f * qi * gkl[1 + i];
      float qsum = 0.0f;
#pragma unroll
      for (int j = 0; j < 16; j++) qsum += qst[t][j] * gkl[17 + i * 16 + j];
      part += C2f * qi * qsum;
    }
    dred[t][p] = part;
  }
  __syncthreads();
  if (tid < 32) {
    float dsum = 0.0f;
    for (int m = 0; m < Mn; m++) dsum += a_s[tid][m];
    float dstt = 0.0f;
#pragma unroll
    for (int p = 0; p < 8; p++) dstt += dred[tid][p];
    zl[tid] = 1.0f / (dstt + dsum);
  }
  __syncthreads();
  const int e4 = (tid & 15) * 4, tq = tid >> 4;
  float ac0[4] = {0, 0, 0, 0}, ac1[4] = {0, 0, 0, 0};
  for (int m = 0; m < Mn; m++) {
    float v4[4];
    *(float4*)v4 = *(const float4*)&vs[m][e4];
    const float a0 = a_s[tq][m], a1 = a_s[tq + 16][m];
#pragma unroll
    for (int j = 0; j < 4; j++) { ac0[j] += a0 * v4[j]; ac1[j] += a1 * v4[j]; }
  }
  const float z0 = zl[tq], z1 = zl[tq + 16];
  float* o0 = att + (size_t)(b * LL + c * CH + t0 + tq) * DM + h * 64 + e4;
  float* o1 = att + (size_t)(b * LL + c * CH + t0 + tq + 16) * DM + h * 64 + e4;
  float4 y0 = *(const float4*)o0;
  float4 y1 = *(const float4*)o1;
  float4 w0, w1;
  w0.x = (y0.x + ac0[0]) * z0; w0.y = (y0.y + ac0[1]) * z0;
  w0.z = (y0.z + ac0[2]) * z0; w0.w = (y0.w + ac0[3]) * z0;
  w1.x = (y1.x + ac1[0]) * z1; w1.y = (y1.y + ac1[1]) * z1;
  w1.z = (y1.z + ac1[2]) * z1; w1.w = (y1.w + ac1[3]) * z1;
  *(float4*)o0 = w0;
  *(float4*)o1 = w1;
}

extern "C" void kernel_launch(void* const* d_in, const int* in_sizes, int n_in,
                              void* d_out, int out_size, void* d_ws, size_t ws_size,
                              hipStream_t stream) {
  const float* hs = (const float*)d_in[0];
  const float* Wq = (const float*)d_in[1];
  const float* Wk = (const float*)d_in[2];
  const float* Wv = (const float*)d_in[3];
  const float* Wo = (const float*)d_in[4];
  float* out = (float*)d_out;
  char* ws = (char*)d_ws;
  // layout (58,713,600 bytes used):
  float* qkv = (float*)(ws);                     // [0, 18874368)
  float* att = (float*)(ws + 18874368);          // [18874368, 31457280)
  char*  regR = ws + 31457280;                   // [31457280, 58294272): Xhat -> csS -> Ahat
  float* csS = (float*)regR;
  float* csk = (float*)(ws + 58294272);          // 419328
  ushortT* Xhat = (ushortT*)regR;                // 4096*1536*2 = 12.6 MB (dead before csS)
  ushortT* What = (ushortT*)att;                 // 1152*1536*2 = 3.5 MB (dead before att)
  ushortT* Wohat = (ushortT*)qkv;                // 768*1536*2 (written after intra)
  ushortT* Ahat = (ushortT*)regR;                // written after state+intra (csS dead)
  const dim3 thr(256);
  // 1-2) pack inputs to [hi|lo] split-bf16
  pack_a<<<3072, thr, 0, stream>>>(hs, Xhat, 4096 * 192);
  pack_w<<<864, thr, 0, stream>>>(Wq, Wk, Wv, 192, 384, What, 1152 * 192);
  // 3) fused QKV projection -> qkv fp32 [4096][1152]; 32 M-tiles x 18 N-tiles, XCD-swizzled
  mfma_gemm<<<576, thr, 0, stream>>>(Xhat, What, qkv, 1152, 18);
  // 4-7) based linear attention
  chunk_sum_kernel<<<NBLK, thr, 0, stream>>>(qkv, csS, csk);
  {
    const int tot = NBH * DEXP * 64 + NBH * DEXP;
    prefix_kernel<<<(tot + 255) / 256, thr, 0, stream>>>(csS, csk);
  }
  state_kernel<<<NBLK, thr, 0, stream>>>(qkv, csS, att);
  intra_kernel<<<dim3(NBLK, 4), thr, 0, stream>>>(qkv, csk, att);
  // 8-9) pack for output projection (qkv and csS regions dead now)
  pack_w<<<576, thr, 0, stream>>>(Wo, Wo, Wo, 768, 768, Wohat, 768 * 192);
  pack_a<<<3072, thr, 0, stream>>>(att, Ahat, 4096 * 192);
  // 10) output projection: 32 M-tiles x 12 N-tiles
  mfma_gemm<<<384, thr, 0, stream>>>(Ahat, Wohat, out, DM, 12);
}

// Round 9
// 262.944 us; speedup vs baseline: 2.3961x; 1.0400x over previous
//
#include <hip/hip_runtime.h>

typedef unsigned short ushortT;
typedef __bf16 bf16x8 __attribute__((ext_vector_type(8)));
typedef float f32x4 __attribute__((ext_vector_type(4)));

// Problem constants
#define BB   2
#define LL   2048
#define DM   768
#define HH   12
#define FT   16
#define HD   64
#define DEXP 273      // 1 + 16 + 256
#define CH   128      // chunk length
#define NC   16       // chunks per sequence (LL/CH)
#define NBH  24       // BB*HH
#define NBLK 384      // NBH*NC
#define C2f  0.17677669529663687f   // 1/(4*sqrt(2))
#define KH   768      // K per half
#define KP   1536     // packed row length: [hi(768) | lo(768)]

// ---------------- split helpers ----------------
__device__ __forceinline__ void split_bf16(float x, ushortT& hi, ushortT& lo) {
  unsigned b = __float_as_uint(x);
  unsigned r = b + 0x7FFFu + ((b >> 16) & 1u);  // RNE to bf16
  hi = (ushortT)(r >> 16);
  float hf = __uint_as_float((unsigned)hi << 16);
  lo = (ushortT)(__float_as_uint(x - hf) >> 16);  // truncate
}

// X [M][768] f32 -> Xh [M][1536] bf16 = [hi | lo]
__global__ __launch_bounds__(256) void pack_a(const float* __restrict__ X,
                                              ushortT* __restrict__ Xh,
                                              int total4) {
  int g = blockIdx.x * 256 + threadIdx.x;
  if (g >= total4) return;
  int m = g / 192, k4 = (g % 192) * 4;
  float4 v = *(const float4*)(X + (size_t)m * 768 + k4);
  ushortT h[4], l[4];
  split_bf16(v.x, h[0], l[0]);
  split_bf16(v.y, h[1], l[1]);
  split_bf16(v.z, h[2], l[2]);
  split_bf16(v.w, h[3], l[3]);
  ushortT* p = Xh + (size_t)m * KP + k4;
  *(ushort4*)p = *(ushort4*)h;
  *(ushort4*)(p + KH) = *(ushort4*)l;
}

// W rows (selected from W0/W1/W2) -> Wh [N][1536] bf16 = [hi | lo]
__global__ __launch_bounds__(256) void pack_w(const float* __restrict__ W0,
                                              const float* __restrict__ W1,
                                              const float* __restrict__ W2,
                                              int n1, int n2,
                                              ushortT* __restrict__ Wh,
                                              int total4) {
  int g = blockIdx.x * 256 + threadIdx.x;
  if (g >= total4) return;
  int n = g / 192, k4 = (g % 192) * 4;
  const float* src = (n < n1 ? W0 + (size_t)n * 768
                    : n < n2 ? W1 + (size_t)(n - n1) * 768
                             : W2 + (size_t)(n - n2) * 768);
  float4 v = *(const float4*)(src + k4);
  ushortT h[4], l[4];
  split_bf16(v.x, h[0], l[0]);
  split_bf16(v.y, h[1], l[1]);
  split_bf16(v.z, h[2], l[2]);
  split_bf16(v.w, h[3], l[3]);
  ushortT* p = Wh + (size_t)n * KP + k4;
  *(ushort4*)p = *(ushort4*)h;
  *(ushort4*)(p + KH) = *(ushort4*)l;
}

// async global->LDS, 16B per lane; lds base must be wave-uniform (lane*16 implicit)
typedef const __attribute__((address_space(1))) unsigned gq_t;
typedef __attribute__((address_space(3))) unsigned lq_t;
__device__ __forceinline__ void gload_lds16(const ushortT* g, ushortT* l) {
  __builtin_amdgcn_global_load_lds((gq_t*)g, (lq_t*)l, 16, 0, 0);
}

// ---------------- MFMA GEMM: Y[M][N] = A[M][KP] @ B[N][KP]^T (3-term split-bf16) -------
__global__ __launch_bounds__(256) void mfma_gemm(const ushortT* __restrict__ A,
                                                 const ushortT* __restrict__ B,
                                                 float* __restrict__ Y, int ldy,
                                                 int ntiles) {
  __shared__ ushortT sAh[128 * 32], sAl[128 * 32], sBh[64 * 32], sBl[64 * 32];
  const int blk = blockIdx.x;
  const int xcd = blk & 7, slot = blk >> 3;
  const int mtp = gridDim.x / (8 * ntiles);
  const int mt = xcd * mtp + slot / ntiles;
  const int nt = slot % ntiles;
  const int bm = mt * 128, bn = nt * 64;
  const int tid = threadIdx.x, wave = tid >> 6, lane = tid & 63;
  const int srow = lane >> 2, schk = (lane & 3) * 8;
  const ushortT* gsrc;
  ushortT* lb;
  int iters;
  switch (wave) {
    case 0:  gsrc = A + (size_t)(bm + srow) * KP + schk;      lb = sAh; iters = 8; break;
    case 1:  gsrc = A + (size_t)(bm + srow) * KP + KH + schk; lb = sAl; iters = 8; break;
    case 2:  gsrc = B + (size_t)(bn + srow) * KP + schk;      lb = sBh; iters = 4; break;
    default: gsrc = B + (size_t)(bn + srow) * KP + KH + schk; lb = sBl; iters = 4; break;
  }
  const int wm = (wave & 1) * 64, wn = (wave >> 1) * 32;
  const int fr = lane & 15, quad = lane >> 4;
  f32x4 acc[4][2] = {};
  for (int k0 = 0; k0 < KH; k0 += 32) {
    __syncthreads();
    for (int it = 0; it < iters; it++)
      gload_lds16(gsrc + k0 + (size_t)it * 16 * KP, lb + it * 512);
    __syncthreads();
    bf16x8 ah[4], al[4], bh2[2], bl2[2];
#pragma unroll
    for (int mi = 0; mi < 4; mi++) {
      ah[mi] = *(const bf16x8*)&sAh[(wm + mi * 16 + fr) * 32 + quad * 8];
      al[mi] = *(const bf16x8*)&sAl[(wm + mi * 16 + fr) * 32 + quad * 8];
    }
#pragma unroll
    for (int ni = 0; ni < 2; ni++) {
      bh2[ni] = *(const bf16x8*)&sBh[(wn + ni * 16 + fr) * 32 + quad * 8];
      bl2[ni] = *(const bf16x8*)&sBl[(wn + ni * 16 + fr) * 32 + quad * 8];
    }
#pragma unroll
    for (int mi = 0; mi < 4; mi++)
#pragma unroll
      for (int ni = 0; ni < 2; ni++) {
        acc[mi][ni] = __builtin_amdgcn_mfma_f32_16x16x32_bf16(ah[mi], bh2[ni], acc[mi][ni], 0, 0, 0);
        acc[mi][ni] = __builtin_amdgcn_mfma_f32_16x16x32_bf16(ah[mi], bl2[ni], acc[mi][ni], 0, 0, 0);
        acc[mi][ni] = __builtin_amdgcn_mfma_f32_16x16x32_bf16(al[mi], bh2[ni], acc[mi][ni], 0, 0, 0);
      }
  }
  const int orow = quad * 4;
#pragma unroll
  for (int mi = 0; mi < 4; mi++)
#pragma unroll
    for (int ni = 0; ni < 2; ni++) {
      float* yp = Y + (size_t)(bm + wm + mi * 16 + orow) * ldy + bn + wn + ni * 16 + fr;
#pragma unroll
      for (int r = 0; r < 4; r++) yp[(size_t)r * ldy] = acc[mi][ni][r];
    }
}

// ---------------- K2: csS = phi_k^T @ V via MFMA (split-bf16 3-term) ----------------
__global__ __launch_bounds__(256, 2) void chunk_sum_kernel(
    const float* __restrict__ qkv, float* __restrict__ csS,
    float* __restrict__ csk) {
  const int blk = blockIdx.x;
  const int bh = blk >> 4, c = blk & 15;
  const int b = bh / HH, h = bh % HH;
  __shared__ float kT[16][128];
  __shared__ ushortT phiA[288][72];
  __shared__ ushortT Vt[64][72];
  const float* base = qkv + (size_t)(b * LL + c * CH) * 1152;
  const int tid = threadIdx.x;
  const int wave = tid >> 6, lane = tid & 63;
  const int fr = lane & 15, quad = lane >> 4;
  for (int idx = tid; idx < 512; idx += 256) {
    int m = idx >> 2, i4 = (idx & 3) * 4;
    float4 k4 = *(const float4*)&base[(size_t)m * 1152 + 192 + h * 16 + i4];
    kT[i4 + 0][m] = k4.x; kT[i4 + 1][m] = k4.y;
    kT[i4 + 2][m] = k4.z; kT[i4 + 3][m] = k4.w;
  }
  const int wm2 = (wave & 1) * 144, wn2 = (wave >> 1) * 32;
  f32x4 acc[9][2] = {};
  __syncthreads();
#pragma unroll 1
  for (int s = 0; s < 4; s++) {
    const int m0 = s * 32;
    if (s) __syncthreads();
    for (int idx = tid; idx < 512; idx += 256) {
      int m = m0 + (idx >> 4), e4 = (idx & 15) * 4;
      float4 v4 = *(const float4*)&base[(size_t)m * 1152 + 384 + h * 64 + e4];
      ushortT hh[4], ll[4];
      split_bf16(v4.x, hh[0], ll[0]); split_bf16(v4.y, hh[1], ll[1]);
      split_bf16(v4.z, hh[2], ll[2]); split_bf16(v4.w, hh[3], ll[3]);
      const int mi2 = m - m0;
#pragma unroll
      for (int j = 0; j < 4; j++) {
        Vt[e4 + j][mi2] = hh[j];
        Vt[e4 + j][32 + mi2] = ll[j];
      }
    }
    for (int rr = tid; rr < 288; rr += 256) {
      const int f = rr;
      const float* pa = (f >= 17) ? kT[(f - 17) >> 4] : (f >= 1 ? kT[f - 1] : kT[0]);
      const float* pb = (f >= 17) ? kT[(f - 17) & 15] : kT[0];
      const float sc = (f == 0) ? 1.0f : (f < 17 ? 0.5f : C2f);
      const bool quadf = (f >= 17);
      const bool valid = (f < DEXP);
      ushortT hrow[32], lrow[32];
#pragma unroll
      for (int g = 0; g < 8; g++) {
        float4 a4 = *(const float4*)&pa[m0 + g * 4];
        float4 b4 = *(const float4*)&pb[m0 + g * 4];
        float v0, v1, v2, v3;
        if (f == 0) {
          v0 = v1 = v2 = v3 = 1.0f;
        } else if (!quadf) {
          v0 = sc * a4.x; v1 = sc * a4.y; v2 = sc * a4.z; v3 = sc * a4.w;
        } else {
          v0 = sc * a4.x * b4.x; v1 = sc * a4.y * b4.y;
          v2 = sc * a4.z * b4.z; v3 = sc * a4.w * b4.w;
        }
        if (!valid) { v0 = v1 = v2 = v3 = 0.0f; }
        split_bf16(v0, hrow[g * 4 + 0], lrow[g * 4 + 0]);
        split_bf16(v1, hrow[g * 4 + 1], lrow[g * 4 + 1]);
        split_bf16(v2, hrow[g * 4 + 2], lrow[g * 4 + 2]);
        split_bf16(v3, hrow[g * 4 + 3], lrow[g * 4 + 3]);
      }
      *(uint4*)&phiA[f][0] = *(uint4*)&hrow[0];
      *(uint4*)&phiA[f][8] = *(uint4*)&hrow[8];
      *(uint4*)&phiA[f][16] = *(uint4*)&hrow[16];
      *(uint4*)&phiA[f][24] = *(uint4*)&hrow[24];
      *(uint4*)&phiA[f][32] = *(uint4*)&lrow[0];
      *(uint4*)&phiA[f][40] = *(uint4*)&lrow[8];
      *(uint4*)&phiA[f][48] = *(uint4*)&lrow[16];
      *(uint4*)&phiA[f][56] = *(uint4*)&lrow[24];
    }
    __syncthreads();
    bf16x8 bhf[2], blf[2];
#pragma unroll
    for (int ni = 0; ni < 2; ni++) {
      bhf[ni] = *(const bf16x8*)&Vt[wn2 + ni * 16 + fr][quad * 8];
      blf[ni] = *(const bf16x8*)&Vt[wn2 + ni * 16 + fr][32 + quad * 8];
    }
#pragma unroll
    for (int mi = 0; mi < 9; mi++) {
      bf16x8 ah = *(const bf16x8*)&phiA[wm2 + mi * 16 + fr][quad * 8];
      bf16x8 al = *(const bf16x8*)&phiA[wm2 + mi * 16 + fr][32 + quad * 8];
#pragma unroll
      for (int ni = 0; ni < 2; ni++) {
        acc[mi][ni] = __builtin_amdgcn_mfma_f32_16x16x32_bf16(ah, bhf[ni], acc[mi][ni], 0, 0, 0);
        acc[mi][ni] = __builtin_amdgcn_mfma_f32_16x16x32_bf16(ah, blf[ni], acc[mi][ni], 0, 0, 0);
        acc[mi][ni] = __builtin_amdgcn_mfma_f32_16x16x32_bf16(al, bhf[ni], acc[mi][ni], 0, 0, 0);
      }
    }
  }
  for (int f = tid; f < DEXP; f += 256) {
    float sum = 0.0f;
    if (f == 0) {
      sum = (float)CH;
    } else if (f < 17) {
      const float* p = kT[f - 1];
      for (int m = 0; m < CH; m += 4) {
        float4 x = *(const float4*)&p[m];
        sum += x.x + x.y + x.z + x.w;
      }
      sum *= 0.5f;
    } else {
      const float* pa2 = kT[(f - 17) >> 4];
      const float* pb2 = kT[(f - 17) & 15];
      for (int m = 0; m < CH; m += 4) {
        float4 x = *(const float4*)&pa2[m];
        float4 y = *(const float4*)&pb2[m];
        sum += x.x * y.x + x.y * y.y + x.z * y.z + x.w * y.w;
      }
      sum *= C2f;
    }
    csk[(size_t)blk * DEXP + f] = sum;
  }
  float* S = csS + (size_t)blk * DEXP * 64;
#pragma unroll
  for (int mi = 0; mi < 9; mi++)
#pragma unroll
    for (int ni = 0; ni < 2; ni++)
#pragma unroll
      for (int r = 0; r < 4; r++) {
        const int f = wm2 + mi * 16 + quad * 4 + r;
        if (f < DEXP) S[(size_t)f * 64 + wn2 + ni * 16 + fr] = acc[mi][ni][r];
      }
}

// ---------------- K3: across-chunk scan ----------------
__global__ __launch_bounds__(256) void prefix_kernel(float* __restrict__ csS,
                                                     float* __restrict__ csk) {
  const int gid = blockIdx.x * 256 + threadIdx.x;
  const int totS = NBH * DEXP * 64;
  if (gid < totS) {
    const int bh = gid / (DEXP * 64);
    const int idx = gid % (DEXP * 64);
    float r[NC];
    float tot = 0.0f;
#pragma unroll
    for (int c = 0; c < NC; c++) {
      r[c] = csS[(size_t)(bh * NC + c) * DEXP * 64 + idx];
      tot += r[c];
    }
    float run = 0.0f;
#pragma unroll
    for (int c = 0; c < NC; c++) {
      csS[(size_t)(bh * NC + c) * DEXP * 64 + idx] = run + tot;
      run += r[c];
    }
  } else {
    const int g2 = gid - totS;
    if (g2 < NBH * DEXP) {
      const int bh = g2 / DEXP;
      const int f = g2 % DEXP;
      float r[NC];
      float tot = 0.0f;
#pragma unroll
      for (int c = 0; c < NC; c++) {
        r[c] = csk[(size_t)(bh * NC + c) * DEXP + f];
        tot += r[c];
      }
      float run = 0.0f;
#pragma unroll
      for (int c = 0; c < NC; c++) {
        csk[(size_t)(bh * NC + c) * DEXP + f] = run + tot;
        run += r[c];
      }
    }
  }
}

// ---------------- fused_out: y = [phi(q)@G + P@V] / d, written packed to Ahat ----------
// grid NBLK. Per block: 128 rows x 64 e. G-phase: 9 K-slabs of 32 features (as R7 state,
// single-buffered; phi(q)*gk accumulated scalar for d). PV-phase: 4 m-slabs of 32;
// scores S = q.k via 2-MFMA trick (A1=[qh|qh],A2=[ql|ql],B=[kh|kl]); poly+mask on C-frag;
// split-bf16 scatter into phiA (A-layout, wave-private rows); P@V MFMA into same acc;
// 5th B-tile (ones row) gives rowsum(P) for the denominator via MFMA.
__global__ __launch_bounds__(256, 2) void fused_out(
    const float* __restrict__ qkv, const float* __restrict__ csS,
    const float* __restrict__ csk, ushortT* __restrict__ Ahat) {
  const int blk = blockIdx.x;
  const int bh = blk >> 4, c = blk & 15;
  const int b = bh / HH, h = bh % HH;
  __shared__ ushortT phiA[128][72];  // G-phase: phi(q) A-panel; PV-phase: P A-panel
  __shared__ ushortT Gt[64][72];     // G-phase: G^T slab; PV-phase: V^T slab
  __shared__ ushortT qA1[128][40];   // [qhi|qhi] (K=32)
  __shared__ ushortT qA2[128][40];   // [qlo|qlo]
  __shared__ ushortT kB[32][40];     // [khi|klo] per m-slab
  __shared__ ushortT onesB[16][72];  // PV ni=4 B-tile: row0 hi=1.0, rest 0
  __shared__ float dred[128][2];
  __shared__ float zl[128];
  const int tid = threadIdx.x;
  const int wv = tid >> 6, lane = tid & 63;
  const int fr = lane & 15, quad = lane >> 4;
  const int prow = tid >> 1, phalf = tid & 1;
  const float* base = qkv + (size_t)(b * LL + c * CH) * 1152;
  const float* qrow = base + (size_t)prow * 1152 + h * 16;
  float qr[16];
#pragma unroll
  for (int i = 0; i < 4; i++) {
    float4 v = *(const float4*)(qrow + i * 4);
    qr[i * 4 + 0] = v.x; qr[i * 4 + 1] = v.y;
    qr[i * 4 + 2] = v.z; qr[i * 4 + 3] = v.w;
  }
  // build qA panels (each thread writes one k-half of its row; halves are duplicates)
  {
    ushortT qh[16], ql[16];
#pragma unroll
    for (int i = 0; i < 16; i++) split_bf16(qr[i], qh[i], ql[i]);
    *(uint4*)&qA1[prow][phalf * 16] = *(uint4*)&qh[0];
    *(uint4*)&qA1[prow][phalf * 16 + 8] = *(uint4*)&qh[8];
    *(uint4*)&qA2[prow][phalf * 16] = *(uint4*)&ql[0];
    *(uint4*)&qA2[prow][phalf * 16 + 8] = *(uint4*)&ql[8];
  }
  // onesB: row 0 k-slots 0..31 (hi region) = 1.0, everything else 0
  for (int idx = tid; idx < 16 * 64; idx += 256) {
    int row = idx >> 6, k = idx & 63;
    onesB[row][k] = (row == 0 && k < 32) ? (ushortT)0x3F80 : (ushortT)0;
  }
  const float* Gc = csS + (size_t)blk * DEXP * 64;
  const float* gkp = csk + (size_t)blk * DEXP;
  const int gfi = tid >> 4, gn4 = (tid & 15) * 4;
  f32x4 acc[2][5] = {};
  float dacc = 0.0f;
  // ---------------- G-phase ----------------
#pragma unroll 1
  for (int s = 0; s < 9; s++) {
    const int f0 = s * 32;
    // stage Gt slab (transpose-split from csS [f][e])
#pragma unroll
    for (int p = 0; p < 2; p++) {
      const int fi = gfi + p * 16;
      const int f = f0 + fi;
      float4 g = make_float4(0.f, 0.f, 0.f, 0.f);
      if (f < DEXP) g = *(const float4*)(Gc + (size_t)f * 64 + gn4);
      ushortT gh[4], gl[4];
      split_bf16(g.x, gh[0], gl[0]);
      split_bf16(g.y, gh[1], gl[1]);
      split_bf16(g.z, gh[2], gl[2]);
      split_bf16(g.w, gh[3], gl[3]);
#pragma unroll
      for (int j = 0; j < 4; j++) {
        Gt[gn4 + j][fi] = gh[j];
        Gt[gn4 + j][32 + fi] = gl[j];
      }
    }
    // stage phi(q) A-panel + accumulate phi*gk for denominator
    {
      ushortT h16[16], l16[16];
#pragma unroll
      for (int j = 0; j < 16; j++) {
        const int f = f0 + phalf * 16 + j;
        float v;
        if (f == 0) v = 1.0f;
        else if (f < 17) v = 0.5f * qr[f - 1];
        else if (f < DEXP) {
          int ii = f - 17;
          v = C2f * qr[ii >> 4] * qr[ii & 15];
        } else v = 0.0f;
        if (f < DEXP) dacc += v * gkp[f];
        split_bf16(v, h16[j], l16[j]);
      }
      *(uint4*)&phiA[prow][phalf * 16] = *(uint4*)&h16[0];
      *(uint4*)&phiA[prow][phalf * 16 + 8] = *(uint4*)&h16[8];
      *(uint4*)&phiA[prow][32 + phalf * 16] = *(uint4*)&l16[0];
      *(uint4*)&phiA[prow][32 + phalf * 16 + 8] = *(uint4*)&l16[8];
    }
    __syncthreads();
    bf16x8 ah[2], al[2];
#pragma unroll
    for (int mi = 0; mi < 2; mi++) {
      ah[mi] = *(const bf16x8*)&phiA[wv * 32 + mi * 16 + fr][quad * 8];
      al[mi] = *(const bf16x8*)&phiA[wv * 32 + mi * 16 + fr][32 + quad * 8];
    }
#pragma unroll
    for (int ni = 0; ni < 4; ni++) {
      bf16x8 bh2 = *(const bf16x8*)&Gt[ni * 16 + fr][quad * 8];
      bf16x8 bl2 = *(const bf16x8*)&Gt[ni * 16 + fr][32 + quad * 8];
#pragma unroll
      for (int mi = 0; mi < 2; mi++) {
        acc[mi][ni] = __builtin_amdgcn_mfma_f32_16x16x32_bf16(ah[mi], bh2, acc[mi][ni], 0, 0, 0);
        acc[mi][ni] = __builtin_amdgcn_mfma_f32_16x16x32_bf16(ah[mi], bl2, acc[mi][ni], 0, 0, 0);
        acc[mi][ni] = __builtin_amdgcn_mfma_f32_16x16x32_bf16(al[mi], bh2, acc[mi][ni], 0, 0, 0);
      }
    }
    __syncthreads();
  }
  dred[prow][phalf] = dacc;
  // ---------------- PV-phase (intra-chunk causal) ----------------
#pragma unroll 1
  for (int s = 0; s < 4; s++) {
    const int m0 = s * 32;
    // stage kB = [khi|klo]
    for (int idx = tid; idx < 128; idx += 256) {
      int mL = idx >> 2, i4 = (idx & 3) * 4;
      float4 k4 = *(const float4*)&base[(size_t)(m0 + mL) * 1152 + 192 + h * 16 + i4];
      ushortT hh[4], ll[4];
      split_bf16(k4.x, hh[0], ll[0]); split_bf16(k4.y, hh[1], ll[1]);
      split_bf16(k4.z, hh[2], ll[2]); split_bf16(k4.w, hh[3], ll[3]);
      *(ushort4*)&kB[mL][i4] = *(ushort4*)hh;
      *(ushort4*)&kB[mL][16 + i4] = *(ushort4*)ll;
    }
    // stage V^T slab into Gt
    for (int idx = tid; idx < 512; idx += 256) {
      int mL = idx >> 4, e4 = (idx & 15) * 4;
      float4 v4 = *(const float4*)&base[(size_t)(m0 + mL) * 1152 + 384 + h * 64 + e4];
      ushortT hh[4], ll[4];
      split_bf16(v4.x, hh[0], ll[0]); split_bf16(v4.y, hh[1], ll[1]);
      split_bf16(v4.z, hh[2], ll[2]); split_bf16(v4.w, hh[3], ll[3]);
#pragma unroll
      for (int j = 0; j < 4; j++) {
        Gt[e4 + j][mL] = hh[j];
        Gt[e4 + j][32 + mL] = ll[j];
      }
    }
    __syncthreads();
    if (s <= wv) {  // causal: slab contributes only to rows >= m0 (wave-uniform)
      // scores -> poly -> mask -> split -> scatter to phiA (wave-private rows)
#pragma unroll
      for (int rt = 0; rt < 2; rt++) {
        bf16x8 a1 = *(const bf16x8*)&qA1[wv * 32 + rt * 16 + fr][quad * 8];
        bf16x8 a2 = *(const bf16x8*)&qA2[wv * 32 + rt * 16 + fr][quad * 8];
#pragma unroll
        for (int mtt = 0; mtt < 2; mtt++) {
          bf16x8 bk = *(const bf16x8*)&kB[mtt * 16 + fr][quad * 8];
          f32x4 sf = {};
          sf = __builtin_amdgcn_mfma_f32_16x16x32_bf16(a1, bk, sf, 0, 0, 0);
          sf = __builtin_amdgcn_mfma_f32_16x16x32_bf16(a2, bk, sf, 0, 0, 0);
          const int mg = m0 + mtt * 16 + fr;
#pragma unroll
          for (int r = 0; r < 4; r++) {
            const int rowL = wv * 32 + rt * 16 + quad * 4 + r;
            const float sv = sf[r];
            const float p = (mg <= rowL) ? fmaf(sv, fmaf(sv, 0.03125f, 0.25f), 1.0f) : 0.0f;
            ushortT ph, pl;
            split_bf16(p, ph, pl);
            phiA[rowL][mtt * 16 + fr] = ph;
            phiA[rowL][32 + mtt * 16 + fr] = pl;
          }
        }
      }
      // P @ V (+ones col for rowsum) — same-wave LDS dependency, no barrier needed
#pragma unroll
      for (int mi = 0; mi < 2; mi++) {
        bf16x8 ah = *(const bf16x8*)&phiA[wv * 32 + mi * 16 + fr][quad * 8];
        bf16x8 al = *(const bf16x8*)&phiA[wv * 32 + mi * 16 + fr][32 + quad * 8];
#pragma unroll
        for (int ni = 0; ni < 5; ni++) {
          bf16x8 bh2 = (ni < 4) ? *(const bf16x8*)&Gt[ni * 16 + fr][quad * 8]
                                : *(const bf16x8*)&onesB[fr][quad * 8];
          bf16x8 bl2 = (ni < 4) ? *(const bf16x8*)&Gt[ni * 16 + fr][32 + quad * 8]
                                : *(const bf16x8*)&onesB[fr][32 + quad * 8];
          acc[mi][ni] = __builtin_amdgcn_mfma_f32_16x16x32_bf16(ah, bh2, acc[mi][ni], 0, 0, 0);
          acc[mi][ni] = __builtin_amdgcn_mfma_f32_16x16x32_bf16(ah, bl2, acc[mi][ni], 0, 0, 0);
          acc[mi][ni] = __builtin_amdgcn_mfma_f32_16x16x32_bf16(al, bh2, acc[mi][ni], 0, 0, 0);
        }
      }
    }
    __syncthreads();
  }
  // ---------------- denominators + epilogue ----------------
  if (fr == 0) {
#pragma unroll
    for (int mi = 0; mi < 2; mi++)
#pragma unroll
      for (int r = 0; r < 4; r++) {
        const int rowL = wv * 32 + mi * 16 + quad * 4 + r;
        const float d = dred[rowL][0] + dred[rowL][1] + acc[mi][4][r];
        zl[rowL] = 1.0f / d;
      }
  }
  __syncthreads();
  const size_t rowbase = (size_t)(b * LL + c * CH);
#pragma unroll
  for (int mi = 0; mi < 2; mi++)
#pragma unroll
    for (int ni = 0; ni < 4; ni++)
#pragma unroll
      for (int r = 0; r < 4; r++) {
        const int rowL = wv * 32 + mi * 16 + quad * 4 + r;
        const float val = acc[mi][ni][r] * zl[rowL];
        ushortT hh, ll;
        split_bf16(val, hh, ll);
        ushortT* ap = Ahat + (rowbase + rowL) * (size_t)KP + h * 64 + ni * 16 + fr;
        ap[0] = hh;
        ap[KH] = ll;
      }
}

extern "C" void kernel_launch(void* const* d_in, const int* in_sizes, int n_in,
                              void* d_out, int out_size, void* d_ws, size_t ws_size,
                              hipStream_t stream) {
  const float* hs = (const float*)d_in[0];
  const float* Wq = (const float*)d_in[1];
  const float* Wk = (const float*)d_in[2];
  const float* Wv = (const float*)d_in[3];
  const float* Wo = (const float*)d_in[4];
  float* out = (float*)d_out;
  char* ws = (char*)d_ws;
  // layout:
  float* qkv = (float*)(ws);                     // [0, 18874368)
  char*  attR = ws + 18874368;                   // [18874368, 31457280): What -> Ahat
  char*  regR = ws + 31457280;                   // [31457280, 58294272): Xhat -> csS
  float* csS = (float*)regR;
  float* csk = (float*)(ws + 58294272);          // 419328
  ushortT* Xhat = (ushortT*)regR;                // 4096*1536*2 = 12.6 MB (dead before csS)
  ushortT* What = (ushortT*)attR;                // 1152*1536*2 = 3.5 MB (dead after QKV gemm)
  ushortT* Ahat = (ushortT*)attR;                // 4096*1536*2 = 12,582,912 (fits region)
  ushortT* Wohat = (ushortT*)qkv;                // 768*1536*2 (written after fused_out)
  const dim3 thr(256);
  // 1-2) pack inputs to [hi|lo] split-bf16
  pack_a<<<3072, thr, 0, stream>>>(hs, Xhat, 4096 * 192);
  pack_w<<<864, thr, 0, stream>>>(Wq, Wk, Wv, 192, 384, What, 1152 * 192);
  // 3) fused QKV projection -> qkv fp32 [4096][1152]
  mfma_gemm<<<576, thr, 0, stream>>>(Xhat, What, qkv, 1152, 18);
  // 4-5) per-chunk sums + across-chunk scan
  chunk_sum_kernel<<<NBLK, thr, 0, stream>>>(qkv, csS, csk);
  {
    const int tot = NBH * DEXP * 64 + NBH * DEXP;
    prefix_kernel<<<(tot + 255) / 256, thr, 0, stream>>>(csS, csk);
  }
  // 6) fused state + intra + scale + pack -> Ahat
  fused_out<<<NBLK, thr, 0, stream>>>(qkv, csS, csk, Ahat);
  // 7) pack Wo (qkv region dead now)
  pack_w<<<576, thr, 0, stream>>>(Wo, Wo, Wo, 768, 768, Wohat, 768 * 192);
  // 8) output projection
  mfma_gemm<<<384, thr, 0, stream>>>(Ahat, Wohat, out, DM, 12);
}